// Round 1
// baseline (563.057 us; speedup 1.0000x reference)
//
#include <hip/hip_runtime.h>
#include <math.h>

#define NB 2
#define NL 1024
#define ND 768
#define NH 12
#define DH 64

typedef _Float16 f16;
typedef _Float16 f16x2 __attribute__((ext_vector_type(2)));
typedef _Float16 f16x4 __attribute__((ext_vector_type(4)));
typedef _Float16 f16x8 __attribute__((ext_vector_type(8)));
typedef float f32x4 __attribute__((ext_vector_type(4)));

#define MFMA16(a, b, c) __builtin_amdgcn_mfma_f32_16x16x32_f16((a), (b), (c), 0, 0, 0)

// LDS-only barrier (does not force vmcnt drain).
__device__ __forceinline__ void soft_barrier() {
    asm volatile("s_waitcnt lgkmcnt(0)\n\ts_barrier" ::: "memory");
}

// ---------------------------------------------------------------------------
// Kernel 0: prep.
//   tiles 0..767    : hs fp32 -> hsf f16
//   tiles 768..1199 : W{q,k,v} -> wt f16 [(mat*12+h)*64+n][k]   (transposed)
//   tiles 1200..1259: ssan_w -> swt f16 [p][h][e][d]            (transposed)
//   tiles 1260..1323: dist_emb fp32 -> de16 f16
// ---------------------------------------------------------------------------
__global__ __launch_bounds__(256) void prep_kernel(
    const float* __restrict__ hs,
    const float* __restrict__ Wq, const float* __restrict__ Wk,
    const float* __restrict__ Wv, const float* __restrict__ sw,
    const float* __restrict__ de,
    f16* __restrict__ hsf, f16* __restrict__ wt, f16* __restrict__ swt,
    f16* __restrict__ de16)
{
    __shared__ float sT[64 * 66];
    const int t = threadIdx.x;
    const int tile = blockIdx.x;

    if (tile < 768) {
        const int base = tile * 2048 + t * 8;
        float4 a = *(const float4*)&hs[base];
        float4 b = *(const float4*)&hs[base + 4];
        f16x8 hv;
        hv[0] = (f16)a.x; hv[1] = (f16)a.y; hv[2] = (f16)a.z; hv[3] = (f16)a.w;
        hv[4] = (f16)b.x; hv[5] = (f16)b.y; hv[6] = (f16)b.z; hv[7] = (f16)b.w;
        *(f16x8*)&hsf[base] = hv;
        return;
    }
    if (tile >= 1260) {
        const int base = (tile - 1260) * 2048 + t * 8;
        if (base < 2047 * 64) {
            float4 a = *(const float4*)&de[base];
            float4 b = *(const float4*)&de[base + 4];
            f16x8 hv;
            hv[0] = (f16)a.x; hv[1] = (f16)a.y; hv[2] = (f16)a.z; hv[3] = (f16)a.w;
            hv[4] = (f16)b.x; hv[5] = (f16)b.y; hv[6] = (f16)b.z; hv[7] = (f16)b.w;
            *(f16x8*)&de16[base] = hv;
        }
        return;
    }

    const float* S; f16* D; int sRS, dRS;
    const int ti = tile - 768;
    if (ti < 432) {
        const int mat = ti / 144, r2 = ti % 144, ht = r2 / 12, kt = r2 % 12;
        const float* W = (mat == 0) ? Wq : (mat == 1) ? Wk : Wv;
        S = W + (size_t)(kt * 64) * ND + ht * 64;
        D = wt + (size_t)((mat * NH + ht) * 64) * ND + kt * 64;
        sRS = ND; dRS = ND;
    } else {
        const int i = ti - 432;
        S = sw + (size_t)i * 4096;
        D = swt + (size_t)i * 4096;
        sRS = 64; dRS = 64;
    }

    {
        const int kk = t >> 2, nb = (t & 3) * 16;
        float v[16];
        #pragma unroll
        for (int j = 0; j < 4; ++j)
            *(float4*)&v[4 * j] = *(const float4*)&S[(size_t)kk * sRS + nb + 4 * j];
        #pragma unroll
        for (int jj = 0; jj < 16; ++jj)
            sT[(nb + jj) * 66 + kk] = v[jj];
    }
    soft_barrier();
    {
        const int n = t >> 2, kb = (t & 3) * 16;
        f16 tmp[16];
        #pragma unroll
        for (int j = 0; j < 8; ++j) {
            float2 x = *(float2*)&sT[n * 66 + kb + 2 * j];
            tmp[2 * j]     = (f16)x.x;
            tmp[2 * j + 1] = (f16)x.y;
        }
        *(f16x8*)&D[(size_t)n * dRS + kb]     = *(f16x8*)&tmp[0];
        *(f16x8*)&D[(size_t)n * dRS + kb + 8] = *(f16x8*)&tmp[8];
    }
}

// ---------------------------------------------------------------------------
// Kernel A: QKV projection, f16 MFMA.  64x64 tile, 4 waves, 2x2 subtiles/wave.
// ---------------------------------------------------------------------------
__global__ __launch_bounds__(256, 4) void qkv_kernel(
    const f16* __restrict__ hsf, const f16* __restrict__ wt,
    const float* __restrict__ bq, const float* __restrict__ bk,
    const float* __restrict__ bv,
    f16* __restrict__ qf, f16* __restrict__ kf, f16* __restrict__ vt)
{
    __shared__ f16 sA[64 * 72], sB[64 * 72];
    __shared__ float sT[64 * 66];

    const int m0  = blockIdx.x * 64;
    const int y   = blockIdx.y;          // 0..35
    const int mat = y / NH, h = y % NH;
    const int t = threadIdx.x, lane = t & 63, w = t >> 6;
    const int quad = lane >> 4, l15 = lane & 15;
    const int wm = w >> 1, wn = w & 1;

    const float* bias = (mat == 0) ? bq : (mat == 1) ? bk : bv;

    f32x4 acc[2][2];
    #pragma unroll
    for (int r = 0; r < 2; ++r)
        #pragma unroll
        for (int c = 0; c < 2; ++c) acc[r][c] = (f32x4){0.f, 0.f, 0.f, 0.f};

    const int srow = t >> 2, scol = (t & 3) * 16;
    const f16* Ag = hsf + (size_t)(m0 + srow) * ND + scol;
    const f16* Bg = wt + ((size_t)y * 64 + srow) * ND + scol;

    for (int k0 = 0; k0 < ND; k0 += 64) {
        soft_barrier();
        *(f16x8*)&sA[srow * 72 + scol]     = *(const f16x8*)&Ag[k0];
        *(f16x8*)&sA[srow * 72 + scol + 8] = *(const f16x8*)&Ag[k0 + 8];
        *(f16x8*)&sB[srow * 72 + scol]     = *(const f16x8*)&Bg[k0];
        *(f16x8*)&sB[srow * 72 + scol + 8] = *(const f16x8*)&Bg[k0 + 8];
        soft_barrier();
        #pragma unroll
        for (int kk = 0; kk < 64; kk += 32) {
            const int ko = kk + quad * 8;
            f16x8 a0 = *(f16x8*)&sA[(32 * wm + l15) * 72 + ko];
            f16x8 a1 = *(f16x8*)&sA[(32 * wm + 16 + l15) * 72 + ko];
            f16x8 b0 = *(f16x8*)&sB[(32 * wn + l15) * 72 + ko];
            f16x8 b1 = *(f16x8*)&sB[(32 * wn + 16 + l15) * 72 + ko];
            acc[0][0] = MFMA16(a0, b0, acc[0][0]);
            acc[0][1] = MFMA16(a0, b1, acc[0][1]);
            acc[1][0] = MFMA16(a1, b0, acc[1][0]);
            acc[1][1] = MFMA16(a1, b1, acc[1][1]);
        }
    }
    soft_barrier();

    const int bb = m0 >> 10;
    const int lbase = m0 & 1023;
    const int bh = bb * NH + h;

    if (mat < 2) {
        #pragma unroll
        for (int r = 0; r < 2; ++r)
            #pragma unroll
            for (int c = 0; c < 2; ++c) {
                const int col = 32 * wn + 16 * c + l15;
                const float bz = bias[h * 64 + col];
                #pragma unroll
                for (int rr = 0; rr < 4; ++rr)
                    sT[(32 * wm + 16 * r + 4 * quad + rr) * 66 + col] = acc[r][c][rr] + bz;
            }
        soft_barrier();
        const int orow = t >> 2, ocb = (t & 3) * 16;
        f16 tmp[16];
        #pragma unroll
        for (int j = 0; j < 8; ++j) {
            float2 x = *(float2*)&sT[orow * 66 + ocb + 2 * j];
            tmp[2 * j] = (f16)x.x; tmp[2 * j + 1] = (f16)x.y;
        }
        f16* dst = ((mat == 0) ? qf : kf) + ((size_t)bh * NL + lbase + orow) * DH + ocb;
        *(f16x8*)dst       = *(f16x8*)&tmp[0];
        *(f16x8*)(dst + 8) = *(f16x8*)&tmp[8];
    } else {
        #pragma unroll
        for (int r = 0; r < 2; ++r)
            #pragma unroll
            for (int c = 0; c < 2; ++c) {
                const int col = 32 * wn + 16 * c + l15;
                const float bz = bias[h * 64 + col];
                #pragma unroll
                for (int rr = 0; rr < 4; ++rr)
                    sT[col * 66 + 32 * wm + 16 * r + 4 * quad + rr] = acc[r][c][rr] + bz;
            }
        soft_barrier();
        const int d = t >> 2, lcb = (t & 3) * 16;
        f16 tmp[16];
        #pragma unroll
        for (int j = 0; j < 8; ++j) {
            float2 x = *(float2*)&sT[d * 66 + lcb + 2 * j];
            tmp[2 * j] = (f16)x.x; tmp[2 * j + 1] = (f16)x.y;
        }
        f16* dst = vt + ((size_t)bh * DH + d) * NL + lbase + lcb;
        *(f16x8*)dst       = *(f16x8*)&tmp[0];
        *(f16x8*)(dst + 8) = *(f16x8*)&tmp[8];
    }
}

// ---------------------------------------------------------------------------
// Kernel B: qw[p,bh,l,e] = qf[bh,l,:] @ ssan_w[p,h]  via f16 MFMA (K=64).
// ---------------------------------------------------------------------------
__global__ __launch_bounds__(256, 4) void qw_kernel(
    const f16* __restrict__ qf, const f16* __restrict__ swt,
    f16* __restrict__ qwf)
{
    __shared__ f16 sA[64 * 72], sB[64 * 72];
    __shared__ float sT[64 * 66];

    const int l0 = blockIdx.x * 64;
    const int z  = blockIdx.y;      // 0..119
    const int p  = z / 24, bh = z % 24, h = bh % NH;
    const int t = threadIdx.x, lane = t & 63, w = t >> 6;
    const int quad = lane >> 4, l15 = lane & 15;
    const int wm = w >> 1, wn = w & 1;

    const int srow = t >> 2, scol = (t & 3) * 16;
    {
        const f16* As = qf + ((size_t)bh * NL + l0 + srow) * DH + scol;
        const f16* Bs = swt + ((size_t)(p * NH + h) * 64 + srow) * 64 + scol;
        *(f16x8*)&sA[srow * 72 + scol]     = *(const f16x8*)As;
        *(f16x8*)&sA[srow * 72 + scol + 8] = *(const f16x8*)(As + 8);
        *(f16x8*)&sB[srow * 72 + scol]     = *(const f16x8*)Bs;
        *(f16x8*)&sB[srow * 72 + scol + 8] = *(const f16x8*)(Bs + 8);
    }
    soft_barrier();

    f32x4 acc[2][2];
    #pragma unroll
    for (int r = 0; r < 2; ++r)
        #pragma unroll
        for (int c = 0; c < 2; ++c) acc[r][c] = (f32x4){0.f, 0.f, 0.f, 0.f};

    #pragma unroll
    for (int kk = 0; kk < 64; kk += 32) {
        const int ko = kk + quad * 8;
        f16x8 a0 = *(f16x8*)&sA[(32 * wm + l15) * 72 + ko];
        f16x8 a1 = *(f16x8*)&sA[(32 * wm + 16 + l15) * 72 + ko];
        f16x8 b0 = *(f16x8*)&sB[(32 * wn + l15) * 72 + ko];
        f16x8 b1 = *(f16x8*)&sB[(32 * wn + 16 + l15) * 72 + ko];
        acc[0][0] = MFMA16(a0, b0, acc[0][0]);
        acc[0][1] = MFMA16(a0, b1, acc[0][1]);
        acc[1][0] = MFMA16(a1, b0, acc[1][0]);
        acc[1][1] = MFMA16(a1, b1, acc[1][1]);
    }
    soft_barrier();

    #pragma unroll
    for (int r = 0; r < 2; ++r)
        #pragma unroll
        for (int c = 0; c < 2; ++c) {
            const int col = 32 * wn + 16 * c + l15;
            #pragma unroll
            for (int rr = 0; rr < 4; ++rr)
                sT[(32 * wm + 16 * r + 4 * quad + rr) * 66 + col] = acc[r][c][rr];
        }
    soft_barrier();

    const int orow = t >> 2, ocb = (t & 3) * 16;
    f16 tmp[16];
    #pragma unroll
    for (int j = 0; j < 8; ++j) {
        float2 x = *(float2*)&sT[orow * 66 + ocb + 2 * j];
        tmp[2 * j] = (f16)x.x; tmp[2 * j + 1] = (f16)x.y;
    }
    f16* dst = qwf + ((size_t)(p * 24 + bh) * NL + l0 + orow) * DH + ocb;
    *(f16x8*)dst       = *(f16x8*)&tmp[0];
    *(f16x8*)(dst + 8) = *(f16x8*)&tmp[8];
}

// ---------------------------------------------------------------------------
// Kernel C: f16-MFMA flash attention with fused positional band-GEMMs.
// 256 threads (4 waves), q-tile 32, k-tile 64.
// Round-8 restructure for occupancy (was 2 blocks/CU, 68 KB LDS):
//   * V single-buffered: next-kt V is reg-staged in phase E (T14 split),
//     ds_written at top of next phase B (-9216 B).
//   * softmax done in MFMA accumulator layout: row-reduce via __shfl_xor
//     over the l15 group + 64-float cross-wave partial arrays; sS / sAlpha /
//     sL deleted (-8960 B).  m/l/alpha now per-lane registers (4 rows/lane).
//   LDS: 50,432 B -> 3 blocks/CU (12 waves/CU, 3 waves/SIMD).
// Per-wave slim tile assignment for band GEMMs (12 MFMA/wave):
//   KE: jt=w, nt=3-w..5-w ;  QE: mi=msub, nt=3*npair+msub .. +qc-1.
// Coverage proof vs tp=i-j+63 ranges in session notes (round 7).
// ---------------------------------------------------------------------------
__global__ __launch_bounds__(256, 3) void attn_kernel(
    const f16* __restrict__ qf, const f16* __restrict__ kf,
    const f16* __restrict__ vt, const f16* __restrict__ qwf,
    const float* __restrict__ mask, const float* __restrict__ struct_m,
    const f16* __restrict__ de16, const float* __restrict__ abs_bias,
    float* __restrict__ out)
{
    __shared__ f16 sK[64 * 72];
    __shared__ f16 sVt[64 * 72];     // single buffer (V reg-staged across kt)
    __shared__ f16 sE[96 * 72];      // E band rows 0..94 (t' = i-j+63)
    __shared__ f16 sQEl[96 * 34];    // [tp][i]
    __shared__ f16 sKEl[96 * 34];    // [tp][j]
    __shared__ f16 sP[32 * 72];
    __shared__ float sMax[64];       // [npair][i] per-wave row-max partials
    __shared__ float sSum[64];       // [npair][i] per-wave row-sum partials

    const int l0 = blockIdx.x * 32;
    const int bh = blockIdx.y;
    const int bb = bh / NH, h = bh % NH;
    const int t  = threadIdx.x;
    const int lane  = t & 63;
    const int w     = t >> 6;       // 0..3
    const int quad  = lane >> 4;
    const int l15   = lane & 15;
    const int msub  = w >> 1;       // 0..1
    const int npair = w & 1;        // 0..1

    const size_t NQKV = (size_t)NB * NH * NL * DH;

    f16x8 aQ[2], aW[5][2];
    {
        const size_t qrow = ((size_t)bh * NL + l0 + 16 * msub + l15) * DH;
        #pragma unroll
        for (int K = 0; K < 2; ++K) {
            aQ[K] = *(const f16x8*)&qf[qrow + 32 * K + 8 * quad];
            #pragma unroll
            for (int p = 0; p < 5; ++p)
                aW[p][K] = *(const f16x8*)&qwf[p * NQKV + qrow + 32 * K + 8 * quad];
        }
    }

    float ab[5];
    #pragma unroll
    for (int p = 0; p < 5; ++p) ab[p] = abs_bias[p * NH + h];

    float pf_st[5][2][4], pf_mask[2];
    f16x8 vreg[2];                   // reg-staged V tile for next kt

    auto stage_k = [&](int r0s) {
        const int row = t >> 3, col = (t & 7) * 8;
        const f16* ks = kf + ((size_t)bh * NL + r0s) * DH;
        *(f16x8*)&sK[row * 72 + col]        = *(const f16x8*)&ks[row * 64 + col];
        *(f16x8*)&sK[(row + 32) * 72 + col] = *(const f16x8*)&ks[(row + 32) * 64 + col];
    };
    auto load_v = [&](int r0s) {
        const int row = t >> 3, col = (t & 7) * 8;
        const f16* vs = vt + (size_t)bh * DH * NL + r0s;
        vreg[0] = *(const f16x8*)&vs[(size_t)row * NL + col];
        vreg[1] = *(const f16x8*)&vs[(size_t)(row + 32) * NL + col];
    };
    auto write_v = [&]() {
        const int row = t >> 3, col = (t & 7) * 8;
        *(f16x8*)&sVt[row * 72 + col]        = vreg[0];
        *(f16x8*)&sVt[(row + 32) * 72 + col] = vreg[1];
    };
    auto stage_E = [&](int r0s) {
        const int ebase = l0 - r0s + 960;
        #pragma unroll
        for (int p2 = 0; p2 < 3; ++p2) {
            const int idx = t + 256 * p2;
            const int er = idx >> 3, col = (idx & 7) * 8;
            if (er < 95)
                *(f16x8*)&sE[er * 72 + col] =
                    *(const f16x8*)&de16[(size_t)(ebase + er) * DH + col];
        }
    };
    auto prefetch = [&](int r0s) {
        #pragma unroll
        for (int n = 0; n < 2; ++n) {
            const int j = 32 * npair + 16 * n + l15;
            pf_mask[n] = mask[bb * NL + r0s + j];
            #pragma unroll
            for (int r = 0; r < 4; ++r) {
                const int i = 16 * msub + 4 * quad + r;
                #pragma unroll
                for (int p = 0; p < 5; ++p)
                    pf_st[p][n][r] =
                        struct_m[((size_t)(p * NB + bb) * NL + l0 + i) * NL + r0s + j];
            }
        }
    };

    stage_k(0);
    stage_E(0);
    load_v(0);
    prefetch(0);

    float m_cur[4], l_cur[4];
    #pragma unroll
    for (int r = 0; r < 4; ++r) { m_cur[r] = -INFINITY; l_cur[r] = 0.f; }
    f32x4 O[2];
    O[0] = (f32x4){0.f, 0.f, 0.f, 0.f};
    O[1] = (f32x4){0.f, 0.f, 0.f, 0.f};

    for (int kt = 0; kt < 16; ++kt) {
        soft_barrier();                    // sK/sE(kt) visible; sVt readers done

        // ---- Phase B: V ds_write + positional band GEMMs ----
        write_v();                          // V(kt): kt=0 from prologue load
        {
            // KE: jt = w, nt = 3-w+c (c = 0..2)
            const int krow = (16 * w + l15) * 72;
            f16x8 ak0 = *(f16x8*)&sK[krow + quad * 8];
            f16x8 ak1 = *(f16x8*)&sK[krow + 32 + quad * 8];
            #pragma unroll
            for (int c = 0; c < 3; ++c) {
                const int nt = 3 - w + c;
                const int erow = (16 * nt + l15) * 72;
                f16x8 e0 = *(f16x8*)&sE[erow + quad * 8];
                f16x8 e1 = *(f16x8*)&sE[erow + 32 + quad * 8];
                f32x4 ck = (f32x4){0.f, 0.f, 0.f, 0.f};
                ck = MFMA16(ak0, e0, ck);
                ck = MFMA16(ak1, e1, ck);
                const int base = (16 * nt + l15) * 34 + 16 * w + 4 * quad;
                f16x2 lo = {(f16)ck[0], (f16)ck[1]};
                f16x2 hi = {(f16)ck[2], (f16)ck[3]};
                *(f16x2*)&sKEl[base]     = lo;
                *(f16x2*)&sKEl[base + 2] = hi;
            }
            // QE: mi = msub, nt = qs..qs+qc-1  (A-frag = resident aQ)
            const int qs = 3 * npair + msub;
            const int qc = 3 - npair;
            #pragma unroll
            for (int c = 0; c < 3; ++c) {
                if (c < qc) {
                    const int nt = qs + c;
                    const int erow = (16 * nt + l15) * 72;
                    f16x8 e0 = *(f16x8*)&sE[erow + quad * 8];
                    f16x8 e1 = *(f16x8*)&sE[erow + 32 + quad * 8];
                    f32x4 cq = (f32x4){0.f, 0.f, 0.f, 0.f};
                    cq = MFMA16(aQ[0], e0, cq);
                    cq = MFMA16(aQ[1], e1, cq);
                    const int base = (16 * nt + l15) * 34 + 16 * msub + 4 * quad;
                    f16x2 lo = {(f16)cq[0], (f16)cq[1]};
                    f16x2 hi = {(f16)cq[2], (f16)cq[3]};
                    *(f16x2*)&sQEl[base]     = lo;
                    *(f16x2*)&sQEl[base + 2] = hi;
                }
            }
        }
        soft_barrier();                    // sQEl/sKEl/sVt published

        // ---- Phase C: score MFMAs + epilogue (pos gather) -> regs ----
        float sv[2][4];
        {
            f32x4 acc[2][6];
            #pragma unroll
            for (int n = 0; n < 2; ++n)
                #pragma unroll
                for (int p = 0; p < 6; ++p)
                    acc[n][p] = (f32x4){0.f, 0.f, 0.f, 0.f};

            __builtin_amdgcn_s_setprio(1);
            #pragma unroll
            for (int K = 0; K < 2; ++K) {
                const int koff = K * 32 + quad * 8;
                f16x8 bk2[2];
                #pragma unroll
                for (int n = 0; n < 2; ++n)
                    bk2[n] = *(f16x8*)&sK[(32 * npair + 16 * n + l15) * 72 + koff];
                #pragma unroll
                for (int n = 0; n < 2; ++n)
                    acc[n][0] = MFMA16(aQ[K], bk2[n], acc[n][0]);
                #pragma unroll
                for (int p = 0; p < 5; ++p)
                    #pragma unroll
                    for (int n = 0; n < 2; ++n)
                        acc[n][1 + p] = MFMA16(aW[p][K], bk2[n], acc[n][1 + p]);
            }
            __builtin_amdgcn_s_setprio(0);

            #pragma unroll
            for (int n = 0; n < 2; ++n) {
                const int j = 32 * npair + 16 * n + l15;
                #pragma unroll
                for (int r = 0; r < 4; ++r) {
                    const int i = 16 * msub + 4 * quad + r;
                    const int tp = i - j + 63;
                    float posv = (float)sQEl[tp * 34 + i] + (float)sKEl[tp * 34 + j];
                    float s = (acc[n][0][r] + posv) * 0.125f + pf_mask[n];
                    #pragma unroll
                    for (int p = 0; p < 5; ++p)
                        s += (acc[n][1 + p][r] + ab[p]) * pf_st[p][n][r];
                    sv[n][r] = s;
                }
            }
        }
        // per-wave row-max over this wave's 32 columns (l15 group reduce)
        {
            float pm[4];
            #pragma unroll
            for (int r = 0; r < 4; ++r) pm[r] = fmaxf(sv[0][r], sv[1][r]);
            #pragma unroll
            for (int off = 8; off > 0; off >>= 1)
                #pragma unroll
                for (int r = 0; r < 4; ++r)
                    pm[r] = fmaxf(pm[r], __shfl_xor(pm[r], off));
            if (l15 == 0) {
                #pragma unroll
                for (int r = 0; r < 4; ++r)
                    sMax[npair * 32 + 16 * msub + 4 * quad + r] = pm[r];
            }
        }
        soft_barrier();                    // sMax published

        // ---- Phase D: in-register online softmax ----
        float alpha[4];
        {
            float ps[4];
            #pragma unroll
            for (int r = 0; r < 4; ++r) {
                const int i = 16 * msub + 4 * quad + r;
                const float m_t = fmaxf(sMax[i], sMax[32 + i]);
                const float m_new = fmaxf(m_cur[r], m_t);
                alpha[r] = __expf(m_cur[r] - m_new);
                const float p0 = __expf(sv[0][r] - m_new);
                const float p1 = __expf(sv[1][r] - m_new);
                m_cur[r] = m_new;
                sP[i * 72 + 32 * npair + l15]      = (f16)p0;
                sP[i * 72 + 32 * npair + 16 + l15] = (f16)p1;
                ps[r] = p0 + p1;
            }
            #pragma unroll
            for (int off = 8; off > 0; off >>= 1)
                #pragma unroll
                for (int r = 0; r < 4; ++r)
                    ps[r] += __shfl_xor(ps[r], off);
            if (l15 == 0) {
                #pragma unroll
                for (int r = 0; r < 4; ++r)
                    sSum[npair * 32 + 16 * msub + 4 * quad + r] = ps[r];
            }
        }
        soft_barrier();                    // sP/sSum published

        // ---- Phase E: l update, next-kt VMEM issue, then PV MFMA ----
        {
            #pragma unroll
            for (int r = 0; r < 4; ++r) {
                const int i = 16 * msub + 4 * quad + r;
                l_cur[r] = l_cur[r] * alpha[r] + sSum[i] + sSum[32 + i];
            }

            if (kt < 15) {
                stage_k((kt + 1) * 64);
                stage_E((kt + 1) * 64);
                load_v((kt + 1) * 64);
                prefetch((kt + 1) * 64);
            }

            #pragma unroll
            for (int n = 0; n < 2; ++n)
                #pragma unroll
                for (int r = 0; r < 4; ++r) O[n][r] *= alpha[r];

            const int prow = (16 * msub + l15) * 72;
            __builtin_amdgcn_s_setprio(1);
            #pragma unroll
            for (int K = 0; K < 2; ++K) {
                const int koff = K * 32 + quad * 8;
                f16x8 pfr = *(f16x8*)&sP[prow + koff];
                #pragma unroll
                for (int n = 0; n < 2; ++n) {
                    f16x8 vfr = *(f16x8*)&sVt[(32 * npair + 16 * n + l15) * 72 + koff];
                    O[n] = MFMA16(pfr, vfr, O[n]);
                }
            }
            __builtin_amdgcn_s_setprio(0);
        }
    }

    float linv[4];
    #pragma unroll
    for (int r = 0; r < 4; ++r) linv[r] = 1.0f / l_cur[r];
    #pragma unroll
    for (int n = 0; n < 2; ++n) {
        const int dh = 32 * npair + 16 * n + l15;
        #pragma unroll
        for (int r = 0; r < 4; ++r) {
            const int i = 16 * msub + 4 * quad + r;
            out[((size_t)bb * NL + l0 + i) * ND + h * DH + dh] = O[n][r] * linv[r];
        }
    }
}

// ---------------------------------------------------------------------------
extern "C" void kernel_launch(void* const* d_in, const int* in_sizes, int n_in,
                              void* d_out, int out_size, void* d_ws, size_t ws_size,
                              hipStream_t stream) {
    const float* hs   = (const float*)d_in[0];
    const float* mask = (const float*)d_in[1];
    const float* stm  = (const float*)d_in[2];
    const float* Wq   = (const float*)d_in[3];
    const float* bq   = (const float*)d_in[4];
    const float* Wk   = (const float*)d_in[5];
    const float* bk   = (const float*)d_in[6];
    const float* Wv   = (const float*)d_in[7];
    const float* bv   = (const float*)d_in[8];
    const float* de   = (const float*)d_in[9];
    const float* sw   = (const float*)d_in[10];
    const float* abb  = (const float*)d_in[11];
    float* outp = (float*)d_out;

    const size_t NQKV = (size_t)NB * NH * NL * DH;       // 1,572,864
    char* ws = (char*)d_ws;
    f16* qf   = (f16*)ws;                 ws += NQKV * 2;
    f16* kf   = (f16*)ws;                 ws += NQKV * 2;
    f16* vtb  = (f16*)ws;                 ws += NQKV * 2;
    f16* qwf  = (f16*)ws;                 ws += 5 * NQKV * 2;
    f16* hsf  = (f16*)ws;                 ws += NQKV * 2;
    f16* wt   = (f16*)ws;                 ws += (size_t)2304 * 768 * 2;
    f16* swt  = (f16*)ws;                 ws += (size_t)245760 * 2;
    f16* de16 = (f16*)ws;                 // 2047*64 f16 = 262 KB

    prep_kernel<<<1324, 256, 0, stream>>>(hs, Wq, Wk, Wv, sw, de,
                                          hsf, wt, swt, de16);
    qkv_kernel<<<dim3(32, 36), 256, 0, stream>>>(hsf, wt, bq, bk, bv, qf, kf, vtb);
    qw_kernel<<<dim3(16, 120), 256, 0, stream>>>(qf, swt, qwf);
    attn_kernel<<<dim3(32, 24), 256, 0, stream>>>(qf, kf, vtb, qwf,
                                                  mask, stm, de16, abb, outp);
}

// Round 2
// 254.806 us; speedup vs baseline: 2.2097x; 2.2097x over previous
//
#include <hip/hip_runtime.h>
#include <math.h>

#define NB 2
#define NL 1024
#define ND 768
#define NH 12
#define DH 64

typedef _Float16 f16;
typedef _Float16 f16x2 __attribute__((ext_vector_type(2)));
typedef _Float16 f16x4 __attribute__((ext_vector_type(4)));
typedef _Float16 f16x8 __attribute__((ext_vector_type(8)));
typedef float f32x4 __attribute__((ext_vector_type(4)));

#define MFMA16(a, b, c) __builtin_amdgcn_mfma_f32_16x16x32_f16((a), (b), (c), 0, 0, 0)

// LDS-only barrier (does not force vmcnt drain).
__device__ __forceinline__ void soft_barrier() {
    asm volatile("s_waitcnt lgkmcnt(0)\n\ts_barrier" ::: "memory");
}

// ---------------------------------------------------------------------------
// Kernel 0: prep.
//   tiles 0..767    : hs fp32 -> hsf f16
//   tiles 768..1199 : W{q,k,v} -> wt f16 [(mat*12+h)*64+n][k]   (transposed)
//   tiles 1200..1259: ssan_w -> swt f16 [p][h][e][d]            (transposed)
//   tiles 1260..1323: dist_emb fp32 -> de16 f16
// ---------------------------------------------------------------------------
__global__ __launch_bounds__(256) void prep_kernel(
    const float* __restrict__ hs,
    const float* __restrict__ Wq, const float* __restrict__ Wk,
    const float* __restrict__ Wv, const float* __restrict__ sw,
    const float* __restrict__ de,
    f16* __restrict__ hsf, f16* __restrict__ wt, f16* __restrict__ swt,
    f16* __restrict__ de16)
{
    __shared__ float sT[64 * 66];
    const int t = threadIdx.x;
    const int tile = blockIdx.x;

    if (tile < 768) {
        const int base = tile * 2048 + t * 8;
        float4 a = *(const float4*)&hs[base];
        float4 b = *(const float4*)&hs[base + 4];
        f16x8 hv;
        hv[0] = (f16)a.x; hv[1] = (f16)a.y; hv[2] = (f16)a.z; hv[3] = (f16)a.w;
        hv[4] = (f16)b.x; hv[5] = (f16)b.y; hv[6] = (f16)b.z; hv[7] = (f16)b.w;
        *(f16x8*)&hsf[base] = hv;
        return;
    }
    if (tile >= 1260) {
        const int base = (tile - 1260) * 2048 + t * 8;
        if (base < 2047 * 64) {
            float4 a = *(const float4*)&de[base];
            float4 b = *(const float4*)&de[base + 4];
            f16x8 hv;
            hv[0] = (f16)a.x; hv[1] = (f16)a.y; hv[2] = (f16)a.z; hv[3] = (f16)a.w;
            hv[4] = (f16)b.x; hv[5] = (f16)b.y; hv[6] = (f16)b.z; hv[7] = (f16)b.w;
            *(f16x8*)&de16[base] = hv;
        }
        return;
    }

    const float* S; f16* D; int sRS, dRS;
    const int ti = tile - 768;
    if (ti < 432) {
        const int mat = ti / 144, r2 = ti % 144, ht = r2 / 12, kt = r2 % 12;
        const float* W = (mat == 0) ? Wq : (mat == 1) ? Wk : Wv;
        S = W + (size_t)(kt * 64) * ND + ht * 64;
        D = wt + (size_t)((mat * NH + ht) * 64) * ND + kt * 64;
        sRS = ND; dRS = ND;
    } else {
        const int i = ti - 432;
        S = sw + (size_t)i * 4096;
        D = swt + (size_t)i * 4096;
        sRS = 64; dRS = 64;
    }

    {
        const int kk = t >> 2, nb = (t & 3) * 16;
        float v[16];
        #pragma unroll
        for (int j = 0; j < 4; ++j)
            *(float4*)&v[4 * j] = *(const float4*)&S[(size_t)kk * sRS + nb + 4 * j];
        #pragma unroll
        for (int jj = 0; jj < 16; ++jj)
            sT[(nb + jj) * 66 + kk] = v[jj];
    }
    soft_barrier();
    {
        const int n = t >> 2, kb = (t & 3) * 16;
        f16 tmp[16];
        #pragma unroll
        for (int j = 0; j < 8; ++j) {
            float2 x = *(float2*)&sT[n * 66 + kb + 2 * j];
            tmp[2 * j]     = (f16)x.x;
            tmp[2 * j + 1] = (f16)x.y;
        }
        *(f16x8*)&D[(size_t)n * dRS + kb]     = *(f16x8*)&tmp[0];
        *(f16x8*)&D[(size_t)n * dRS + kb + 8] = *(f16x8*)&tmp[8];
    }
}

// ---------------------------------------------------------------------------
// Kernel A: QKV projection, f16 MFMA.  64x64 tile, 4 waves, 2x2 subtiles/wave.
// ---------------------------------------------------------------------------
__global__ __launch_bounds__(256, 4) void qkv_kernel(
    const f16* __restrict__ hsf, const f16* __restrict__ wt,
    const float* __restrict__ bq, const float* __restrict__ bk,
    const float* __restrict__ bv,
    f16* __restrict__ qf, f16* __restrict__ kf, f16* __restrict__ vt)
{
    __shared__ f16 sA[64 * 72], sB[64 * 72];
    __shared__ float sT[64 * 66];

    const int m0  = blockIdx.x * 64;
    const int y   = blockIdx.y;          // 0..35
    const int mat = y / NH, h = y % NH;
    const int t = threadIdx.x, lane = t & 63, w = t >> 6;
    const int quad = lane >> 4, l15 = lane & 15;
    const int wm = w >> 1, wn = w & 1;

    const float* bias = (mat == 0) ? bq : (mat == 1) ? bk : bv;

    f32x4 acc[2][2];
    #pragma unroll
    for (int r = 0; r < 2; ++r)
        #pragma unroll
        for (int c = 0; c < 2; ++c) acc[r][c] = (f32x4){0.f, 0.f, 0.f, 0.f};

    const int srow = t >> 2, scol = (t & 3) * 16;
    const f16* Ag = hsf + (size_t)(m0 + srow) * ND + scol;
    const f16* Bg = wt + ((size_t)y * 64 + srow) * ND + scol;

    for (int k0 = 0; k0 < ND; k0 += 64) {
        soft_barrier();
        *(f16x8*)&sA[srow * 72 + scol]     = *(const f16x8*)&Ag[k0];
        *(f16x8*)&sA[srow * 72 + scol + 8] = *(const f16x8*)&Ag[k0 + 8];
        *(f16x8*)&sB[srow * 72 + scol]     = *(const f16x8*)&Bg[k0];
        *(f16x8*)&sB[srow * 72 + scol + 8] = *(const f16x8*)&Bg[k0 + 8];
        soft_barrier();
        #pragma unroll
        for (int kk = 0; kk < 64; kk += 32) {
            const int ko = kk + quad * 8;
            f16x8 a0 = *(f16x8*)&sA[(32 * wm + l15) * 72 + ko];
            f16x8 a1 = *(f16x8*)&sA[(32 * wm + 16 + l15) * 72 + ko];
            f16x8 b0 = *(f16x8*)&sB[(32 * wn + l15) * 72 + ko];
            f16x8 b1 = *(f16x8*)&sB[(32 * wn + 16 + l15) * 72 + ko];
            acc[0][0] = MFMA16(a0, b0, acc[0][0]);
            acc[0][1] = MFMA16(a0, b1, acc[0][1]);
            acc[1][0] = MFMA16(a1, b0, acc[1][0]);
            acc[1][1] = MFMA16(a1, b1, acc[1][1]);
        }
    }
    soft_barrier();

    const int bb = m0 >> 10;
    const int lbase = m0 & 1023;
    const int bh = bb * NH + h;

    if (mat < 2) {
        #pragma unroll
        for (int r = 0; r < 2; ++r)
            #pragma unroll
            for (int c = 0; c < 2; ++c) {
                const int col = 32 * wn + 16 * c + l15;
                const float bz = bias[h * 64 + col];
                #pragma unroll
                for (int rr = 0; rr < 4; ++rr)
                    sT[(32 * wm + 16 * r + 4 * quad + rr) * 66 + col] = acc[r][c][rr] + bz;
            }
        soft_barrier();
        const int orow = t >> 2, ocb = (t & 3) * 16;
        f16 tmp[16];
        #pragma unroll
        for (int j = 0; j < 8; ++j) {
            float2 x = *(float2*)&sT[orow * 66 + ocb + 2 * j];
            tmp[2 * j] = (f16)x.x; tmp[2 * j + 1] = (f16)x.y;
        }
        f16* dst = ((mat == 0) ? qf : kf) + ((size_t)bh * NL + lbase + orow) * DH + ocb;
        *(f16x8*)dst       = *(f16x8*)&tmp[0];
        *(f16x8*)(dst + 8) = *(f16x8*)&tmp[8];
    } else {
        #pragma unroll
        for (int r = 0; r < 2; ++r)
            #pragma unroll
            for (int c = 0; c < 2; ++c) {
                const int col = 32 * wn + 16 * c + l15;
                const float bz = bias[h * 64 + col];
                #pragma unroll
                for (int rr = 0; rr < 4; ++rr)
                    sT[col * 66 + 32 * wm + 16 * r + 4 * quad + rr] = acc[r][c][rr] + bz;
            }
        soft_barrier();
        const int d = t >> 2, lcb = (t & 3) * 16;
        f16 tmp[16];
        #pragma unroll
        for (int j = 0; j < 8; ++j) {
            float2 x = *(float2*)&sT[d * 66 + lcb + 2 * j];
            tmp[2 * j] = (f16)x.x; tmp[2 * j + 1] = (f16)x.y;
        }
        f16* dst = vt + ((size_t)bh * DH + d) * NL + lbase + lcb;
        *(f16x8*)dst       = *(f16x8*)&tmp[0];
        *(f16x8*)(dst + 8) = *(f16x8*)&tmp[8];
    }
}

// ---------------------------------------------------------------------------
// Kernel B: qw[p,bh,l,e] = qf[bh,l,:] @ ssan_w[p,h]  via f16 MFMA (K=64).
// ---------------------------------------------------------------------------
__global__ __launch_bounds__(256, 4) void qw_kernel(
    const f16* __restrict__ qf, const f16* __restrict__ swt,
    f16* __restrict__ qwf)
{
    __shared__ f16 sA[64 * 72], sB[64 * 72];
    __shared__ float sT[64 * 66];

    const int l0 = blockIdx.x * 64;
    const int z  = blockIdx.y;      // 0..119
    const int p  = z / 24, bh = z % 24, h = bh % NH;
    const int t = threadIdx.x, lane = t & 63, w = t >> 6;
    const int quad = lane >> 4, l15 = lane & 15;
    const int wm = w >> 1, wn = w & 1;

    const int srow = t >> 2, scol = (t & 3) * 16;
    {
        const f16* As = qf + ((size_t)bh * NL + l0 + srow) * DH + scol;
        const f16* Bs = swt + ((size_t)(p * NH + h) * 64 + srow) * 64 + scol;
        *(f16x8*)&sA[srow * 72 + scol]     = *(const f16x8*)As;
        *(f16x8*)&sA[srow * 72 + scol + 8] = *(const f16x8*)(As + 8);
        *(f16x8*)&sB[srow * 72 + scol]     = *(const f16x8*)Bs;
        *(f16x8*)&sB[srow * 72 + scol + 8] = *(const f16x8*)(Bs + 8);
    }
    soft_barrier();

    f32x4 acc[2][2];
    #pragma unroll
    for (int r = 0; r < 2; ++r)
        #pragma unroll
        for (int c = 0; c < 2; ++c) acc[r][c] = (f32x4){0.f, 0.f, 0.f, 0.f};

    #pragma unroll
    for (int kk = 0; kk < 64; kk += 32) {
        const int ko = kk + quad * 8;
        f16x8 a0 = *(f16x8*)&sA[(32 * wm + l15) * 72 + ko];
        f16x8 a1 = *(f16x8*)&sA[(32 * wm + 16 + l15) * 72 + ko];
        f16x8 b0 = *(f16x8*)&sB[(32 * wn + l15) * 72 + ko];
        f16x8 b1 = *(f16x8*)&sB[(32 * wn + 16 + l15) * 72 + ko];
        acc[0][0] = MFMA16(a0, b0, acc[0][0]);
        acc[0][1] = MFMA16(a0, b1, acc[0][1]);
        acc[1][0] = MFMA16(a1, b0, acc[1][0]);
        acc[1][1] = MFMA16(a1, b1, acc[1][1]);
    }
    soft_barrier();

    #pragma unroll
    for (int r = 0; r < 2; ++r)
        #pragma unroll
        for (int c = 0; c < 2; ++c) {
            const int col = 32 * wn + 16 * c + l15;
            #pragma unroll
            for (int rr = 0; rr < 4; ++rr)
                sT[(32 * wm + 16 * r + 4 * quad + rr) * 66 + col] = acc[r][c][rr];
        }
    soft_barrier();

    const int orow = t >> 2, ocb = (t & 3) * 16;
    f16 tmp[16];
    #pragma unroll
    for (int j = 0; j < 8; ++j) {
        float2 x = *(float2*)&sT[orow * 66 + ocb + 2 * j];
        tmp[2 * j] = (f16)x.x; tmp[2 * j + 1] = (f16)x.y;
    }
    f16* dst = qwf + ((size_t)(p * 24 + bh) * NL + l0 + orow) * DH + ocb;
    *(f16x8*)dst       = *(f16x8*)&tmp[0];
    *(f16x8*)(dst + 8) = *(f16x8*)&tmp[8];
}

// ---------------------------------------------------------------------------
// Kernel C: f16-MFMA flash attention with fused positional band-GEMMs.
// 256 threads (4 waves), q-tile 32, k-tile 64.
// Round-9: LDS 50,688 B (3 blocks/CU possible) + in-register online softmax
// (sS/sAlpha/sL deleted; V single-buffered, reg-staged across kt).
// launch_bounds (256,2): round-8's (256,3) clamp forced VGPR->84 and spilled
// pf_st/vreg to scratch (WRITE_SIZE 6MB->443MB, 3.5x slower).  With (256,2)
// the allocator is free (~130-150 VGPR expected); HW occupancy comes from
// ACTUAL usage: <=170 VGPR -> 3 waves/SIMD, LDS-capped at 3 blocks/CU.
// Per-wave slim tile assignment for band GEMMs (12 MFMA/wave):
//   KE: jt=w, nt=3-w..5-w ;  QE: mi=msub, nt=3*npair+msub .. +qc-1.
// Coverage proof vs tp=i-j+63 ranges in session notes (round 7).
// ---------------------------------------------------------------------------
__global__ __launch_bounds__(256, 2) void attn_kernel(
    const f16* __restrict__ qf, const f16* __restrict__ kf,
    const f16* __restrict__ vt, const f16* __restrict__ qwf,
    const float* __restrict__ mask, const float* __restrict__ struct_m,
    const f16* __restrict__ de16, const float* __restrict__ abs_bias,
    float* __restrict__ out)
{
    __shared__ f16 sK[64 * 72];
    __shared__ f16 sVt[64 * 72];     // single buffer (V reg-staged across kt)
    __shared__ f16 sE[96 * 72];      // E band rows 0..94 (t' = i-j+63)
    __shared__ f16 sQEl[96 * 34];    // [tp][i]
    __shared__ f16 sKEl[96 * 34];    // [tp][j]
    __shared__ f16 sP[32 * 72];
    __shared__ float sMax[64];       // [npair][i] per-wave row-max partials
    __shared__ float sSum[64];       // [npair][i] per-wave row-sum partials

    const int l0 = blockIdx.x * 32;
    const int bh = blockIdx.y;
    const int bb = bh / NH, h = bh % NH;
    const int t  = threadIdx.x;
    const int lane  = t & 63;
    const int w     = t >> 6;       // 0..3
    const int quad  = lane >> 4;
    const int l15   = lane & 15;
    const int msub  = w >> 1;       // 0..1
    const int npair = w & 1;        // 0..1

    const size_t NQKV = (size_t)NB * NH * NL * DH;

    f16x8 aQ[2], aW[5][2];
    {
        const size_t qrow = ((size_t)bh * NL + l0 + 16 * msub + l15) * DH;
        #pragma unroll
        for (int K = 0; K < 2; ++K) {
            aQ[K] = *(const f16x8*)&qf[qrow + 32 * K + 8 * quad];
            #pragma unroll
            for (int p = 0; p < 5; ++p)
                aW[p][K] = *(const f16x8*)&qwf[p * NQKV + qrow + 32 * K + 8 * quad];
        }
    }

    float ab[5];
    #pragma unroll
    for (int p = 0; p < 5; ++p) ab[p] = abs_bias[p * NH + h];

    float pf_st[5][2][4], pf_mask[2];
    f16x8 vreg[2];                   // reg-staged V tile for next kt

    auto stage_k = [&](int r0s) {
        const int row = t >> 3, col = (t & 7) * 8;
        const f16* ks = kf + ((size_t)bh * NL + r0s) * DH;
        *(f16x8*)&sK[row * 72 + col]        = *(const f16x8*)&ks[row * 64 + col];
        *(f16x8*)&sK[(row + 32) * 72 + col] = *(const f16x8*)&ks[(row + 32) * 64 + col];
    };
    auto load_v = [&](int r0s) {
        const int row = t >> 3, col = (t & 7) * 8;
        const f16* vs = vt + (size_t)bh * DH * NL + r0s;
        vreg[0] = *(const f16x8*)&vs[(size_t)row * NL + col];
        vreg[1] = *(const f16x8*)&vs[(size_t)(row + 32) * NL + col];
    };
    auto write_v = [&]() {
        const int row = t >> 3, col = (t & 7) * 8;
        *(f16x8*)&sVt[row * 72 + col]        = vreg[0];
        *(f16x8*)&sVt[(row + 32) * 72 + col] = vreg[1];
    };
    auto stage_E = [&](int r0s) {
        const int ebase = l0 - r0s + 960;
        #pragma unroll
        for (int p2 = 0; p2 < 3; ++p2) {
            const int idx = t + 256 * p2;
            const int er = idx >> 3, col = (idx & 7) * 8;
            if (er < 95)
                *(f16x8*)&sE[er * 72 + col] =
                    *(const f16x8*)&de16[(size_t)(ebase + er) * DH + col];
        }
    };
    auto prefetch = [&](int r0s) {
        #pragma unroll
        for (int n = 0; n < 2; ++n) {
            const int j = 32 * npair + 16 * n + l15;
            pf_mask[n] = mask[bb * NL + r0s + j];
            #pragma unroll
            for (int r = 0; r < 4; ++r) {
                const int i = 16 * msub + 4 * quad + r;
                #pragma unroll
                for (int p = 0; p < 5; ++p)
                    pf_st[p][n][r] =
                        struct_m[((size_t)(p * NB + bb) * NL + l0 + i) * NL + r0s + j];
            }
        }
    };

    stage_k(0);
    stage_E(0);
    load_v(0);
    prefetch(0);

    float m_cur[4], l_cur[4];
    #pragma unroll
    for (int r = 0; r < 4; ++r) { m_cur[r] = -INFINITY; l_cur[r] = 0.f; }
    f32x4 O[2];
    O[0] = (f32x4){0.f, 0.f, 0.f, 0.f};
    O[1] = (f32x4){0.f, 0.f, 0.f, 0.f};

    for (int kt = 0; kt < 16; ++kt) {
        soft_barrier();                    // sK/sE(kt) visible; sVt readers done

        // ---- Phase B: V ds_write + positional band GEMMs ----
        write_v();                          // V(kt): kt=0 from prologue load
        {
            // KE: jt = w, nt = 3-w+c (c = 0..2)
            const int krow = (16 * w + l15) * 72;
            f16x8 ak0 = *(f16x8*)&sK[krow + quad * 8];
            f16x8 ak1 = *(f16x8*)&sK[krow + 32 + quad * 8];
            #pragma unroll
            for (int c = 0; c < 3; ++c) {
                const int nt = 3 - w + c;
                const int erow = (16 * nt + l15) * 72;
                f16x8 e0 = *(f16x8*)&sE[erow + quad * 8];
                f16x8 e1 = *(f16x8*)&sE[erow + 32 + quad * 8];
                f32x4 ck = (f32x4){0.f, 0.f, 0.f, 0.f};
                ck = MFMA16(ak0, e0, ck);
                ck = MFMA16(ak1, e1, ck);
                const int base = (16 * nt + l15) * 34 + 16 * w + 4 * quad;
                f16x2 lo = {(f16)ck[0], (f16)ck[1]};
                f16x2 hi = {(f16)ck[2], (f16)ck[3]};
                *(f16x2*)&sKEl[base]     = lo;
                *(f16x2*)&sKEl[base + 2] = hi;
            }
            // QE: mi = msub, nt = qs..qs+qc-1  (A-frag = resident aQ)
            const int qs = 3 * npair + msub;
            const int qc = 3 - npair;
            #pragma unroll
            for (int c = 0; c < 3; ++c) {
                if (c < qc) {
                    const int nt = qs + c;
                    const int erow = (16 * nt + l15) * 72;
                    f16x8 e0 = *(f16x8*)&sE[erow + quad * 8];
                    f16x8 e1 = *(f16x8*)&sE[erow + 32 + quad * 8];
                    f32x4 cq = (f32x4){0.f, 0.f, 0.f, 0.f};
                    cq = MFMA16(aQ[0], e0, cq);
                    cq = MFMA16(aQ[1], e1, cq);
                    const int base = (16 * nt + l15) * 34 + 16 * msub + 4 * quad;
                    f16x2 lo = {(f16)cq[0], (f16)cq[1]};
                    f16x2 hi = {(f16)cq[2], (f16)cq[3]};
                    *(f16x2*)&sQEl[base]     = lo;
                    *(f16x2*)&sQEl[base + 2] = hi;
                }
            }
        }
        soft_barrier();                    // sQEl/sKEl/sVt published

        // ---- Phase C: score MFMAs + epilogue (pos gather) -> regs ----
        float sv[2][4];
        {
            f32x4 acc[2][6];
            #pragma unroll
            for (int n = 0; n < 2; ++n)
                #pragma unroll
                for (int p = 0; p < 6; ++p)
                    acc[n][p] = (f32x4){0.f, 0.f, 0.f, 0.f};

            __builtin_amdgcn_s_setprio(1);
            #pragma unroll
            for (int K = 0; K < 2; ++K) {
                const int koff = K * 32 + quad * 8;
                f16x8 bk2[2];
                #pragma unroll
                for (int n = 0; n < 2; ++n)
                    bk2[n] = *(f16x8*)&sK[(32 * npair + 16 * n + l15) * 72 + koff];
                #pragma unroll
                for (int n = 0; n < 2; ++n)
                    acc[n][0] = MFMA16(aQ[K], bk2[n], acc[n][0]);
                #pragma unroll
                for (int p = 0; p < 5; ++p)
                    #pragma unroll
                    for (int n = 0; n < 2; ++n)
                        acc[n][1 + p] = MFMA16(aW[p][K], bk2[n], acc[n][1 + p]);
            }
            __builtin_amdgcn_s_setprio(0);

            #pragma unroll
            for (int n = 0; n < 2; ++n) {
                const int j = 32 * npair + 16 * n + l15;
                #pragma unroll
                for (int r = 0; r < 4; ++r) {
                    const int i = 16 * msub + 4 * quad + r;
                    const int tp = i - j + 63;
                    float posv = (float)sQEl[tp * 34 + i] + (float)sKEl[tp * 34 + j];
                    float s = (acc[n][0][r] + posv) * 0.125f + pf_mask[n];
                    #pragma unroll
                    for (int p = 0; p < 5; ++p)
                        s += (acc[n][1 + p][r] + ab[p]) * pf_st[p][n][r];
                    sv[n][r] = s;
                }
            }
        }
        // per-wave row-max over this wave's 32 columns (l15 group reduce)
        {
            float pm[4];
            #pragma unroll
            for (int r = 0; r < 4; ++r) pm[r] = fmaxf(sv[0][r], sv[1][r]);
            #pragma unroll
            for (int off = 8; off > 0; off >>= 1)
                #pragma unroll
                for (int r = 0; r < 4; ++r)
                    pm[r] = fmaxf(pm[r], __shfl_xor(pm[r], off));
            if (l15 == 0) {
                #pragma unroll
                for (int r = 0; r < 4; ++r)
                    sMax[npair * 32 + 16 * msub + 4 * quad + r] = pm[r];
            }
        }
        soft_barrier();                    // sMax published

        // ---- Phase D: in-register online softmax ----
        float alpha[4];
        {
            float ps[4];
            #pragma unroll
            for (int r = 0; r < 4; ++r) {
                const int i = 16 * msub + 4 * quad + r;
                const float m_t = fmaxf(sMax[i], sMax[32 + i]);
                const float m_new = fmaxf(m_cur[r], m_t);
                alpha[r] = __expf(m_cur[r] - m_new);
                const float p0 = __expf(sv[0][r] - m_new);
                const float p1 = __expf(sv[1][r] - m_new);
                m_cur[r] = m_new;
                sP[i * 72 + 32 * npair + l15]      = (f16)p0;
                sP[i * 72 + 32 * npair + 16 + l15] = (f16)p1;
                ps[r] = p0 + p1;
            }
            #pragma unroll
            for (int off = 8; off > 0; off >>= 1)
                #pragma unroll
                for (int r = 0; r < 4; ++r)
                    ps[r] += __shfl_xor(ps[r], off);
            if (l15 == 0) {
                #pragma unroll
                for (int r = 0; r < 4; ++r)
                    sSum[npair * 32 + 16 * msub + 4 * quad + r] = ps[r];
            }
        }
        soft_barrier();                    // sP/sSum published

        // ---- Phase E: l update, next-kt VMEM issue, then PV MFMA ----
        {
            #pragma unroll
            for (int r = 0; r < 4; ++r) {
                const int i = 16 * msub + 4 * quad + r;
                l_cur[r] = l_cur[r] * alpha[r] + sSum[i] + sSum[32 + i];
            }

            if (kt < 15) {
                stage_k((kt + 1) * 64);
                stage_E((kt + 1) * 64);
                load_v((kt + 1) * 64);
                prefetch((kt + 1) * 64);
            }

            #pragma unroll
            for (int n = 0; n < 2; ++n)
                #pragma unroll
                for (int r = 0; r < 4; ++r) O[n][r] *= alpha[r];

            const int prow = (16 * msub + l15) * 72;
            __builtin_amdgcn_s_setprio(1);
            #pragma unroll
            for (int K = 0; K < 2; ++K) {
                const int koff = K * 32 + quad * 8;
                f16x8 pfr = *(f16x8*)&sP[prow + koff];
                #pragma unroll
                for (int n = 0; n < 2; ++n) {
                    f16x8 vfr = *(f16x8*)&sVt[(32 * npair + 16 * n + l15) * 72 + koff];
                    O[n] = MFMA16(pfr, vfr, O[n]);
                }
            }
            __builtin_amdgcn_s_setprio(0);
        }
    }

    float linv[4];
    #pragma unroll
    for (int r = 0; r < 4; ++r) linv[r] = 1.0f / l_cur[r];
    #pragma unroll
    for (int n = 0; n < 2; ++n) {
        const int dh = 32 * npair + 16 * n + l15;
        #pragma unroll
        for (int r = 0; r < 4; ++r) {
            const int i = 16 * msub + 4 * quad + r;
            out[((size_t)bb * NL + l0 + i) * ND + h * DH + dh] = O[n][r] * linv[r];
        }
    }
}

// ---------------------------------------------------------------------------
extern "C" void kernel_launch(void* const* d_in, const int* in_sizes, int n_in,
                              void* d_out, int out_size, void* d_ws, size_t ws_size,
                              hipStream_t stream) {
    const float* hs   = (const float*)d_in[0];
    const float* mask = (const float*)d_in[1];
    const float* stm  = (const float*)d_in[2];
    const float* Wq   = (const float*)d_in[3];
    const float* bq   = (const float*)d_in[4];
    const float* Wk   = (const float*)d_in[5];
    const float* bk   = (const float*)d_in[6];
    const float* Wv   = (const float*)d_in[7];
    const float* bv   = (const float*)d_in[8];
    const float* de   = (const float*)d_in[9];
    const float* sw   = (const float*)d_in[10];
    const float* abb  = (const float*)d_in[11];
    float* outp = (float*)d_out;

    const size_t NQKV = (size_t)NB * NH * NL * DH;       // 1,572,864
    char* ws = (char*)d_ws;
    f16* qf   = (f16*)ws;                 ws += NQKV * 2;
    f16* kf   = (f16*)ws;                 ws += NQKV * 2;
    f16* vtb  = (f16*)ws;                 ws += NQKV * 2;
    f16* qwf  = (f16*)ws;                 ws += 5 * NQKV * 2;
    f16* hsf  = (f16*)ws;                 ws += NQKV * 2;
    f16* wt   = (f16*)ws;                 ws += (size_t)2304 * 768 * 2;
    f16* swt  = (f16*)ws;                 ws += (size_t)245760 * 2;
    f16* de16 = (f16*)ws;                 // 2047*64 f16 = 262 KB

    prep_kernel<<<1324, 256, 0, stream>>>(hs, Wq, Wk, Wv, sw, de,
                                          hsf, wt, swt, de16);
    qkv_kernel<<<dim3(32, 36), 256, 0, stream>>>(hsf, wt, bq, bk, bv, qf, kf, vtb);
    qw_kernel<<<dim3(16, 120), 256, 0, stream>>>(qf, swt, qwf);
    attn_kernel<<<dim3(32, 24), 256, 0, stream>>>(qf, kf, vtb, qwf,
                                                  mask, stm, de16, abb, outp);
}

// Round 3
// 230.857 us; speedup vs baseline: 2.4390x; 1.1037x over previous
//
#include <hip/hip_runtime.h>
#include <math.h>

#define NB 2
#define NL 1024
#define ND 768
#define NH 12
#define DH 64

typedef _Float16 f16;
typedef _Float16 f16x2 __attribute__((ext_vector_type(2)));
typedef _Float16 f16x4 __attribute__((ext_vector_type(4)));
typedef _Float16 f16x8 __attribute__((ext_vector_type(8)));
typedef float f32x4 __attribute__((ext_vector_type(4)));

#define MFMA16(a, b, c) __builtin_amdgcn_mfma_f32_16x16x32_f16((a), (b), (c), 0, 0, 0)

// LDS-only barrier (does not force vmcnt drain).
__device__ __forceinline__ void soft_barrier() {
    asm volatile("s_waitcnt lgkmcnt(0)\n\ts_barrier" ::: "memory");
}

// ---------------------------------------------------------------------------
// Kernel 0: prep.
//   tiles 0..767    : hs fp32 -> hsf f16
//   tiles 768..1199 : W{q,k,v} -> wt f16 [(mat*12+h)*64+n][k]   (transposed)
//   tiles 1200..1259: ssan_w -> swt f16 [p][h][e][d]            (transposed)
//   tiles 1260..1323: dist_emb fp32 -> de16 f16
// ---------------------------------------------------------------------------
__global__ __launch_bounds__(256) void prep_kernel(
    const float* __restrict__ hs,
    const float* __restrict__ Wq, const float* __restrict__ Wk,
    const float* __restrict__ Wv, const float* __restrict__ sw,
    const float* __restrict__ de,
    f16* __restrict__ hsf, f16* __restrict__ wt, f16* __restrict__ swt,
    f16* __restrict__ de16)
{
    __shared__ float sT[64 * 66];
    const int t = threadIdx.x;
    const int tile = blockIdx.x;

    if (tile < 768) {
        const int base = tile * 2048 + t * 8;
        float4 a = *(const float4*)&hs[base];
        float4 b = *(const float4*)&hs[base + 4];
        f16x8 hv;
        hv[0] = (f16)a.x; hv[1] = (f16)a.y; hv[2] = (f16)a.z; hv[3] = (f16)a.w;
        hv[4] = (f16)b.x; hv[5] = (f16)b.y; hv[6] = (f16)b.z; hv[7] = (f16)b.w;
        *(f16x8*)&hsf[base] = hv;
        return;
    }
    if (tile >= 1260) {
        const int base = (tile - 1260) * 2048 + t * 8;
        if (base < 2047 * 64) {
            float4 a = *(const float4*)&de[base];
            float4 b = *(const float4*)&de[base + 4];
            f16x8 hv;
            hv[0] = (f16)a.x; hv[1] = (f16)a.y; hv[2] = (f16)a.z; hv[3] = (f16)a.w;
            hv[4] = (f16)b.x; hv[5] = (f16)b.y; hv[6] = (f16)b.z; hv[7] = (f16)b.w;
            *(f16x8*)&de16[base] = hv;
        }
        return;
    }

    const float* S; f16* D; int sRS, dRS;
    const int ti = tile - 768;
    if (ti < 432) {
        const int mat = ti / 144, r2 = ti % 144, ht = r2 / 12, kt = r2 % 12;
        const float* W = (mat == 0) ? Wq : (mat == 1) ? Wk : Wv;
        S = W + (size_t)(kt * 64) * ND + ht * 64;
        D = wt + (size_t)((mat * NH + ht) * 64) * ND + kt * 64;
        sRS = ND; dRS = ND;
    } else {
        const int i = ti - 432;
        S = sw + (size_t)i * 4096;
        D = swt + (size_t)i * 4096;
        sRS = 64; dRS = 64;
    }

    {
        const int kk = t >> 2, nb = (t & 3) * 16;
        float v[16];
        #pragma unroll
        for (int j = 0; j < 4; ++j)
            *(float4*)&v[4 * j] = *(const float4*)&S[(size_t)kk * sRS + nb + 4 * j];
        #pragma unroll
        for (int jj = 0; jj < 16; ++jj)
            sT[(nb + jj) * 66 + kk] = v[jj];
    }
    soft_barrier();
    {
        const int n = t >> 2, kb = (t & 3) * 16;
        f16 tmp[16];
        #pragma unroll
        for (int j = 0; j < 8; ++j) {
            float2 x = *(float2*)&sT[n * 66 + kb + 2 * j];
            tmp[2 * j]     = (f16)x.x;
            tmp[2 * j + 1] = (f16)x.y;
        }
        *(f16x8*)&D[(size_t)n * dRS + kb]     = *(f16x8*)&tmp[0];
        *(f16x8*)&D[(size_t)n * dRS + kb + 8] = *(f16x8*)&tmp[8];
    }
}

// ---------------------------------------------------------------------------
// Kernel A: QKV projection, f16 MFMA.  64x64 tile, 4 waves, 2x2 subtiles/wave.
// ---------------------------------------------------------------------------
__global__ __launch_bounds__(256, 4) void qkv_kernel(
    const f16* __restrict__ hsf, const f16* __restrict__ wt,
    const float* __restrict__ bq, const float* __restrict__ bk,
    const float* __restrict__ bv,
    f16* __restrict__ qf, f16* __restrict__ kf, f16* __restrict__ vt)
{
    __shared__ f16 sA[64 * 72], sB[64 * 72];
    __shared__ float sT[64 * 66];

    const int m0  = blockIdx.x * 64;
    const int y   = blockIdx.y;          // 0..35
    const int mat = y / NH, h = y % NH;
    const int t = threadIdx.x, lane = t & 63, w = t >> 6;
    const int quad = lane >> 4, l15 = lane & 15;
    const int wm = w >> 1, wn = w & 1;

    const float* bias = (mat == 0) ? bq : (mat == 1) ? bk : bv;

    f32x4 acc[2][2];
    #pragma unroll
    for (int r = 0; r < 2; ++r)
        #pragma unroll
        for (int c = 0; c < 2; ++c) acc[r][c] = (f32x4){0.f, 0.f, 0.f, 0.f};

    const int srow = t >> 2, scol = (t & 3) * 16;
    const f16* Ag = hsf + (size_t)(m0 + srow) * ND + scol;
    const f16* Bg = wt + ((size_t)y * 64 + srow) * ND + scol;

    for (int k0 = 0; k0 < ND; k0 += 64) {
        soft_barrier();
        *(f16x8*)&sA[srow * 72 + scol]     = *(const f16x8*)&Ag[k0];
        *(f16x8*)&sA[srow * 72 + scol + 8] = *(const f16x8*)&Ag[k0 + 8];
        *(f16x8*)&sB[srow * 72 + scol]     = *(const f16x8*)&Bg[k0];
        *(f16x8*)&sB[srow * 72 + scol + 8] = *(const f16x8*)&Bg[k0 + 8];
        soft_barrier();
        #pragma unroll
        for (int kk = 0; kk < 64; kk += 32) {
            const int ko = kk + quad * 8;
            f16x8 a0 = *(f16x8*)&sA[(32 * wm + l15) * 72 + ko];
            f16x8 a1 = *(f16x8*)&sA[(32 * wm + 16 + l15) * 72 + ko];
            f16x8 b0 = *(f16x8*)&sB[(32 * wn + l15) * 72 + ko];
            f16x8 b1 = *(f16x8*)&sB[(32 * wn + 16 + l15) * 72 + ko];
            acc[0][0] = MFMA16(a0, b0, acc[0][0]);
            acc[0][1] = MFMA16(a0, b1, acc[0][1]);
            acc[1][0] = MFMA16(a1, b0, acc[1][0]);
            acc[1][1] = MFMA16(a1, b1, acc[1][1]);
        }
    }
    soft_barrier();

    const int bb = m0 >> 10;
    const int lbase = m0 & 1023;
    const int bh = bb * NH + h;

    if (mat < 2) {
        #pragma unroll
        for (int r = 0; r < 2; ++r)
            #pragma unroll
            for (int c = 0; c < 2; ++c) {
                const int col = 32 * wn + 16 * c + l15;
                const float bz = bias[h * 64 + col];
                #pragma unroll
                for (int rr = 0; rr < 4; ++rr)
                    sT[(32 * wm + 16 * r + 4 * quad + rr) * 66 + col] = acc[r][c][rr] + bz;
            }
        soft_barrier();
        const int orow = t >> 2, ocb = (t & 3) * 16;
        f16 tmp[16];
        #pragma unroll
        for (int j = 0; j < 8; ++j) {
            float2 x = *(float2*)&sT[orow * 66 + ocb + 2 * j];
            tmp[2 * j] = (f16)x.x; tmp[2 * j + 1] = (f16)x.y;
        }
        f16* dst = ((mat == 0) ? qf : kf) + ((size_t)bh * NL + lbase + orow) * DH + ocb;
        *(f16x8*)dst       = *(f16x8*)&tmp[0];
        *(f16x8*)(dst + 8) = *(f16x8*)&tmp[8];
    } else {
        #pragma unroll
        for (int r = 0; r < 2; ++r)
            #pragma unroll
            for (int c = 0; c < 2; ++c) {
                const int col = 32 * wn + 16 * c + l15;
                const float bz = bias[h * 64 + col];
                #pragma unroll
                for (int rr = 0; rr < 4; ++rr)
                    sT[col * 66 + 32 * wm + 16 * r + 4 * quad + rr] = acc[r][c][rr] + bz;
            }
        soft_barrier();
        const int d = t >> 2, lcb = (t & 3) * 16;
        f16 tmp[16];
        #pragma unroll
        for (int j = 0; j < 8; ++j) {
            float2 x = *(float2*)&sT[d * 66 + lcb + 2 * j];
            tmp[2 * j] = (f16)x.x; tmp[2 * j + 1] = (f16)x.y;
        }
        f16* dst = vt + ((size_t)bh * DH + d) * NL + lbase + lcb;
        *(f16x8*)dst       = *(f16x8*)&tmp[0];
        *(f16x8*)(dst + 8) = *(f16x8*)&tmp[8];
    }
}

// ---------------------------------------------------------------------------
// Kernel C: f16-MFMA flash attention with fused positional band-GEMMs AND
// fused qw = Q @ ssan_w[p,h] (round-10: qw_kernel + qwf eliminated; each
// (bh,row) lives in exactly one attn block, so the prologue computes the
// exact aW fragments the block needs: 20 MFMA/wave + one LDS round trip
// through sE scratch, in 2 batches of {3,2} planes (3*32*72 = 6912 = |sE|).
// Body = round-0 structure (proven 126us; rounds 8-9 in-reg softmax was
// slower at 137us and (256,3) clamp spilled -> 441us).
// 256 threads (4 waves), q-tile 32, k-tile 64, __launch_bounds__(256,2).
// Per-wave slim tile assignment (12 MFMA/wave):
//   KE: jt=w, nt=3-w..5-w ;  QE: mi=msub, nt=3*npair+msub .. +qc-1.
// ---------------------------------------------------------------------------
__global__ __launch_bounds__(256, 2) void attn_kernel(
    const f16* __restrict__ qf, const f16* __restrict__ kf,
    const f16* __restrict__ vt, const f16* __restrict__ swt,
    const float* __restrict__ mask, const float* __restrict__ struct_m,
    const f16* __restrict__ de16, const float* __restrict__ abs_bias,
    float* __restrict__ out)
{
    __shared__ f16 sK[64 * 72];
    __shared__ f16 sVt[2][64 * 72];
    __shared__ f16 sE[96 * 72];      // E band rows 0..94 (t' = i-j+63); also qw scratch in prologue
    __shared__ f16 sQEl[96 * 34];    // [tp][i]
    __shared__ f16 sKEl[96 * 34];    // [tp][j]
    __shared__ float sS[32 * 68];
    __shared__ f16 sP[32 * 72];
    __shared__ float sAlpha[32], sL[32];

    const int l0 = blockIdx.x * 32;
    const int bh = blockIdx.y;
    const int bb = bh / NH, h = bh % NH;
    const int t  = threadIdx.x;
    const int lane  = t & 63;
    const int w     = t >> 6;       // 0..3
    const int quad  = lane >> 4;
    const int l15   = lane & 15;
    const int msub  = w >> 1;       // 0..1
    const int npair = w & 1;        // 0..1

    f16x8 aQ[2], aW[5][2];
    {
        const size_t qrow = ((size_t)bh * NL + l0 + 16 * msub + l15) * DH;
        #pragma unroll
        for (int K = 0; K < 2; ++K)
            aQ[K] = *(const f16x8*)&qf[qrow + 32 * K + 8 * quad];
    }

    // ---- Fused qw: aW[p] fragments of Q_tile @ ssan_w[p,h] ----
    // Wave layout: msub splits rows (2x16), npair splits e-tiles (2x2).
    // C layout per MFMA: row = 4*quad+r, col = l15  ->  scratch [pi][i][e].
    {
        #pragma unroll
        for (int b = 0; b < 2; ++b) {
            const int pb0  = (b == 0) ? 0 : 3;
            const int pcnt = (b == 0) ? 3 : 2;
            #pragma unroll
            for (int pi = 0; pi < 3; ++pi) {
                if (pi < pcnt) {
                    const int p = pb0 + pi;
                    const f16* Wp = swt + ((size_t)(p * NH + h)) * 64 * 64;
                    #pragma unroll
                    for (int ntl = 0; ntl < 2; ++ntl) {
                        const int nt = 2 * npair + ntl;
                        f32x4 c = (f32x4){0.f, 0.f, 0.f, 0.f};
                        #pragma unroll
                        for (int K = 0; K < 2; ++K) {
                            f16x8 bw = *(const f16x8*)&Wp[(size_t)(16 * nt + l15) * 64 + 32 * K + 8 * quad];
                            c = MFMA16(aQ[K], bw, c);
                        }
                        #pragma unroll
                        for (int r = 0; r < 4; ++r)
                            sE[(pi * 32 + 16 * msub + 4 * quad + r) * 72 + 16 * nt + l15] = (f16)c[r];
                    }
                }
            }
            soft_barrier();                 // scratch planes published
            #pragma unroll
            for (int pi = 0; pi < 3; ++pi) {
                if (pi < pcnt) {
                    #pragma unroll
                    for (int K = 0; K < 2; ++K)
                        aW[pb0 + pi][K] =
                            *(const f16x8*)&sE[(pi * 32 + 16 * msub + l15) * 72 + 32 * K + 8 * quad];
                }
            }
            soft_barrier();                 // reads done before scratch reuse
        }
    }

    float ab[5];
    #pragma unroll
    for (int p = 0; p < 5; ++p) ab[p] = abs_bias[p * NH + h];

    float pf_st[5][2][4], pf_mask[2];

    auto stage_kv = [&](int r0s, int buf) {
        const int row = t >> 3, col = (t & 7) * 8;
        const f16* ks = kf + ((size_t)bh * NL + r0s) * DH;
        *(f16x8*)&sK[row * 72 + col]        = *(const f16x8*)&ks[row * 64 + col];
        *(f16x8*)&sK[(row + 32) * 72 + col] = *(const f16x8*)&ks[(row + 32) * 64 + col];
        const f16* vs = vt + (size_t)bh * DH * NL + r0s;
        *(f16x8*)&sVt[buf][row * 72 + col] =
            *(const f16x8*)&vs[(size_t)row * NL + col];
        *(f16x8*)&sVt[buf][(row + 32) * 72 + col] =
            *(const f16x8*)&vs[(size_t)(row + 32) * NL + col];
    };
    auto stage_E = [&](int r0s) {
        const int ebase = l0 - r0s + 960;
        #pragma unroll
        for (int p2 = 0; p2 < 3; ++p2) {
            const int idx = t + 256 * p2;
            const int er = idx >> 3, col = (idx & 7) * 8;
            if (er < 95)
                *(f16x8*)&sE[er * 72 + col] =
                    *(const f16x8*)&de16[(size_t)(ebase + er) * DH + col];
        }
    };
    auto prefetch = [&](int r0s) {
        #pragma unroll
        for (int n = 0; n < 2; ++n) {
            const int j = 32 * npair + 16 * n + l15;
            pf_mask[n] = mask[bb * NL + r0s + j];
            #pragma unroll
            for (int r = 0; r < 4; ++r) {
                const int i = 16 * msub + 4 * quad + r;
                #pragma unroll
                for (int p = 0; p < 5; ++p)
                    pf_st[p][n][r] =
                        struct_m[((size_t)(p * NB + bb) * NL + l0 + i) * NL + r0s + j];
            }
        }
    };

    stage_kv(0, 0);
    stage_E(0);
    prefetch(0);

    const int sm_i = t >> 3;
    const int sm_jb = t & 7;
    float m_cur = -INFINITY, l_cur = 0.f;
    f32x4 O[2];
    O[0] = (f32x4){0.f, 0.f, 0.f, 0.f};
    O[1] = (f32x4){0.f, 0.f, 0.f, 0.f};

    for (int kt = 0; kt < 16; ++kt) {
        const int cur = kt & 1;
        soft_barrier();                    // staging of this kt visible

        // ---- Phase B: positional band GEMMs (slim per-wave assignment) ----
        {
            // KE: jt = w, nt = 3-w+c (c = 0..2)
            const int krow = (16 * w + l15) * 72;
            f16x8 ak0 = *(f16x8*)&sK[krow + quad * 8];
            f16x8 ak1 = *(f16x8*)&sK[krow + 32 + quad * 8];
            #pragma unroll
            for (int c = 0; c < 3; ++c) {
                const int nt = 3 - w + c;
                const int erow = (16 * nt + l15) * 72;
                f16x8 e0 = *(f16x8*)&sE[erow + quad * 8];
                f16x8 e1 = *(f16x8*)&sE[erow + 32 + quad * 8];
                f32x4 ck = (f32x4){0.f, 0.f, 0.f, 0.f};
                ck = MFMA16(ak0, e0, ck);
                ck = MFMA16(ak1, e1, ck);
                const int base = (16 * nt + l15) * 34 + 16 * w + 4 * quad;
                f16x2 lo = {(f16)ck[0], (f16)ck[1]};
                f16x2 hi = {(f16)ck[2], (f16)ck[3]};
                *(f16x2*)&sKEl[base]     = lo;
                *(f16x2*)&sKEl[base + 2] = hi;
            }
            // QE: mi = msub, nt = qs..qs+qc-1  (A-frag = resident aQ)
            const int qs = 3 * npair + msub;
            const int qc = 3 - npair;
            #pragma unroll
            for (int c = 0; c < 3; ++c) {
                if (c < qc) {
                    const int nt = qs + c;
                    const int erow = (16 * nt + l15) * 72;
                    f16x8 e0 = *(f16x8*)&sE[erow + quad * 8];
                    f16x8 e1 = *(f16x8*)&sE[erow + 32 + quad * 8];
                    f32x4 cq = (f32x4){0.f, 0.f, 0.f, 0.f};
                    cq = MFMA16(aQ[0], e0, cq);
                    cq = MFMA16(aQ[1], e1, cq);
                    const int base = (16 * nt + l15) * 34 + 16 * msub + 4 * quad;
                    f16x2 lo = {(f16)cq[0], (f16)cq[1]};
                    f16x2 hi = {(f16)cq[2], (f16)cq[3]};
                    *(f16x2*)&sQEl[base]     = lo;
                    *(f16x2*)&sQEl[base + 2] = hi;
                }
            }
        }
        soft_barrier();                    // sQEl/sKEl published

        // ---- Phase C: score MFMAs + epilogue (pos gather) ----
        {
            f32x4 acc[2][6];
            #pragma unroll
            for (int n = 0; n < 2; ++n)
                #pragma unroll
                for (int p = 0; p < 6; ++p)
                    acc[n][p] = (f32x4){0.f, 0.f, 0.f, 0.f};

            #pragma unroll
            for (int K = 0; K < 2; ++K) {
                const int koff = K * 32 + quad * 8;
                f16x8 bk2[2];
                #pragma unroll
                for (int n = 0; n < 2; ++n)
                    bk2[n] = *(f16x8*)&sK[(32 * npair + 16 * n + l15) * 72 + koff];
                #pragma unroll
                for (int n = 0; n < 2; ++n)
                    acc[n][0] = MFMA16(aQ[K], bk2[n], acc[n][0]);
                #pragma unroll
                for (int p = 0; p < 5; ++p)
                    #pragma unroll
                    for (int n = 0; n < 2; ++n)
                        acc[n][1 + p] = MFMA16(aW[p][K], bk2[n], acc[n][1 + p]);
            }

            #pragma unroll
            for (int n = 0; n < 2; ++n) {
                const int j = 32 * npair + 16 * n + l15;
                #pragma unroll
                for (int r = 0; r < 4; ++r) {
                    const int i = 16 * msub + 4 * quad + r;
                    const int tp = i - j + 63;
                    float posv = (float)sQEl[tp * 34 + i] + (float)sKEl[tp * 34 + j];
                    float s = (acc[n][0][r] + posv) * 0.125f + pf_mask[n];
                    #pragma unroll
                    for (int p = 0; p < 5; ++p)
                        s += (acc[n][1 + p][r] + ab[p]) * pf_st[p][n][r];
                    sS[i * 68 + j] = s;
                }
            }
        }
        soft_barrier();                    // sS published

        // ---- Phase D: online softmax ----
        {
            float sv[8];
            float smax = -INFINITY;
            #pragma unroll
            for (int k = 0; k < 8; ++k) {
                sv[k] = sS[sm_i * 68 + sm_jb + 8 * k];
                smax = fmaxf(smax, sv[k]);
            }
            #pragma unroll
            for (int off = 4; off > 0; off >>= 1)
                smax = fmaxf(smax, __shfl_xor(smax, off, 8));
            const float m_new = fmaxf(m_cur, smax);
            const float alpha = __expf(m_cur - m_new);
            float rsum = 0.f;
            #pragma unroll
            for (int k = 0; k < 8; ++k) {
                float p = __expf(sv[k] - m_new);
                sP[sm_i * 72 + sm_jb + 8 * k] = (f16)p;
                rsum += p;
            }
            #pragma unroll
            for (int off = 4; off > 0; off >>= 1)
                rsum += __shfl_xor(rsum, off, 8);
            l_cur = l_cur * alpha + rsum;
            m_cur = m_new;
            if (sm_jb == 0) { sAlpha[sm_i] = alpha; sL[sm_i] = l_cur; }
        }
        soft_barrier();                    // sP/alpha published

        // ---- Phase E: issue next-kt VMEM first, then PV MFMA ----
        {
            if (kt < 15) {
                stage_kv((kt + 1) * 64, cur ^ 1);
                stage_E((kt + 1) * 64);
                prefetch((kt + 1) * 64);
            }

            float a4[4];
            #pragma unroll
            for (int r = 0; r < 4; ++r) a4[r] = sAlpha[16 * msub + 4 * quad + r];
            #pragma unroll
            for (int n = 0; n < 2; ++n)
                #pragma unroll
                for (int r = 0; r < 4; ++r) O[n][r] *= a4[r];

            const int prow = (16 * msub + l15) * 72;
            #pragma unroll
            for (int K = 0; K < 2; ++K) {
                const int koff = K * 32 + quad * 8;
                f16x8 pfr = *(f16x8*)&sP[prow + koff];
                #pragma unroll
                for (int n = 0; n < 2; ++n) {
                    f16x8 vfr = *(f16x8*)&sVt[cur][(32 * npair + 16 * n + l15) * 72 + koff];
                    O[n] = MFMA16(pfr, vfr, O[n]);
                }
            }
        }
    }

    float linv[4];
    #pragma unroll
    for (int r = 0; r < 4; ++r) linv[r] = 1.0f / sL[16 * msub + 4 * quad + r];
    #pragma unroll
    for (int n = 0; n < 2; ++n) {
        const int dh = 32 * npair + 16 * n + l15;
        #pragma unroll
        for (int r = 0; r < 4; ++r) {
            const int i = 16 * msub + 4 * quad + r;
            out[((size_t)bb * NL + l0 + i) * ND + h * DH + dh] = O[n][r] * linv[r];
        }
    }
}

// ---------------------------------------------------------------------------
extern "C" void kernel_launch(void* const* d_in, const int* in_sizes, int n_in,
                              void* d_out, int out_size, void* d_ws, size_t ws_size,
                              hipStream_t stream) {
    const float* hs   = (const float*)d_in[0];
    const float* mask = (const float*)d_in[1];
    const float* stm  = (const float*)d_in[2];
    const float* Wq   = (const float*)d_in[3];
    const float* bq   = (const float*)d_in[4];
    const float* Wk   = (const float*)d_in[5];
    const float* bk   = (const float*)d_in[6];
    const float* Wv   = (const float*)d_in[7];
    const float* bv   = (const float*)d_in[8];
    const float* de   = (const float*)d_in[9];
    const float* sw   = (const float*)d_in[10];
    const float* abb  = (const float*)d_in[11];
    float* outp = (float*)d_out;

    const size_t NQKV = (size_t)NB * NH * NL * DH;       // 1,572,864
    char* ws = (char*)d_ws;
    f16* qf   = (f16*)ws;                 ws += NQKV * 2;
    f16* kf   = (f16*)ws;                 ws += NQKV * 2;
    f16* vtb  = (f16*)ws;                 ws += NQKV * 2;
    f16* hsf  = (f16*)ws;                 ws += NQKV * 2;
    f16* wt   = (f16*)ws;                 ws += (size_t)2304 * 768 * 2;
    f16* swt  = (f16*)ws;                 ws += (size_t)245760 * 2;
    f16* de16 = (f16*)ws;                 // 2047*64 f16 = 262 KB

    prep_kernel<<<1324, 256, 0, stream>>>(hs, Wq, Wk, Wv, sw, de,
                                          hsf, wt, swt, de16);
    qkv_kernel<<<dim3(32, 36), 256, 0, stream>>>(hsf, wt, bq, bk, bv, qf, kf, vtb);
    attn_kernel<<<dim3(32, 24), 256, 0, stream>>>(qf, kf, vtb, swt,
                                                  mask, stm, de16, abb, outp);
}

// Round 4
// 219.989 us; speedup vs baseline: 2.5595x; 1.0494x over previous
//
#include <hip/hip_runtime.h>
#include <math.h>

#define NB 2
#define NL 1024
#define ND 768
#define NH 12
#define DH 64

typedef _Float16 f16;
typedef _Float16 f16x2 __attribute__((ext_vector_type(2)));
typedef _Float16 f16x4 __attribute__((ext_vector_type(4)));
typedef _Float16 f16x8 __attribute__((ext_vector_type(8)));
typedef float f32x4 __attribute__((ext_vector_type(4)));

#define MFMA16(a, b, c) __builtin_amdgcn_mfma_f32_16x16x32_f16((a), (b), (c), 0, 0, 0)

// LDS-only barrier (does not force vmcnt drain).
__device__ __forceinline__ void soft_barrier() {
    asm volatile("s_waitcnt lgkmcnt(0)\n\ts_barrier" ::: "memory");
}

// ---------------------------------------------------------------------------
// Kernel 0: prep (round-11: hs->f16 conversion folded into qkv; 556 tiles).
//   tiles 0..431   : W{q,k,v} -> wt f16 [(mat*12+h)*64+n][k]   (transposed)
//   tiles 432..491 : ssan_w -> swt f16 [p][h][e][d]            (transposed)
//   tiles 492..555 : dist_emb fp32 -> de16 f16
// ---------------------------------------------------------------------------
__global__ __launch_bounds__(256) void prep_kernel(
    const float* __restrict__ Wq, const float* __restrict__ Wk,
    const float* __restrict__ Wv, const float* __restrict__ sw,
    const float* __restrict__ de,
    f16* __restrict__ wt, f16* __restrict__ swt, f16* __restrict__ de16)
{
    __shared__ float sT[64 * 66];
    const int t = threadIdx.x;
    const int tile = blockIdx.x;

    if (tile >= 492) {
        const int base = (tile - 492) * 2048 + t * 8;
        if (base < 2047 * 64) {
            float4 a = *(const float4*)&de[base];
            float4 b = *(const float4*)&de[base + 4];
            f16x8 hv;
            hv[0] = (f16)a.x; hv[1] = (f16)a.y; hv[2] = (f16)a.z; hv[3] = (f16)a.w;
            hv[4] = (f16)b.x; hv[5] = (f16)b.y; hv[6] = (f16)b.z; hv[7] = (f16)b.w;
            *(f16x8*)&de16[base] = hv;
        }
        return;
    }

    const float* S; f16* D; int sRS, dRS;
    if (tile < 432) {
        const int mat = tile / 144, r2 = tile % 144, ht = r2 / 12, kt = r2 % 12;
        const float* W = (mat == 0) ? Wq : (mat == 1) ? Wk : Wv;
        S = W + (size_t)(kt * 64) * ND + ht * 64;
        D = wt + (size_t)((mat * NH + ht) * 64) * ND + kt * 64;
        sRS = ND; dRS = ND;
    } else {
        const int i = tile - 432;
        S = sw + (size_t)i * 4096;
        D = swt + (size_t)i * 4096;
        sRS = 64; dRS = 64;
    }

    {
        const int kk = t >> 2, nb = (t & 3) * 16;
        float v[16];
        #pragma unroll
        for (int j = 0; j < 4; ++j)
            *(float4*)&v[4 * j] = *(const float4*)&S[(size_t)kk * sRS + nb + 4 * j];
        #pragma unroll
        for (int jj = 0; jj < 16; ++jj)
            sT[(nb + jj) * 66 + kk] = v[jj];
    }
    soft_barrier();
    {
        const int n = t >> 2, kb = (t & 3) * 16;
        f16 tmp[16];
        #pragma unroll
        for (int j = 0; j < 8; ++j) {
            float2 x = *(float2*)&sT[n * 66 + kb + 2 * j];
            tmp[2 * j]     = (f16)x.x;
            tmp[2 * j + 1] = (f16)x.y;
        }
        *(f16x8*)&D[(size_t)n * dRS + kb]     = *(f16x8*)&tmp[0];
        *(f16x8*)&D[(size_t)n * dRS + kb + 8] = *(f16x8*)&tmp[8];
    }
}

// ---------------------------------------------------------------------------
// Kernel A: QKV projection, f16 MFMA.  64x64 tile, 4 waves, 2x2 subtiles/wave.
// Round-11: A-operand read directly from hs (fp32) with in-register f16
// conversion — hsf buffer and 768 prep tiles deleted.
// ---------------------------------------------------------------------------
__global__ __launch_bounds__(256, 4) void qkv_kernel(
    const float* __restrict__ hs, const f16* __restrict__ wt,
    const float* __restrict__ bq, const float* __restrict__ bk,
    const float* __restrict__ bv,
    f16* __restrict__ qf, f16* __restrict__ kf, f16* __restrict__ vt)
{
    __shared__ f16 sA[64 * 72], sB[64 * 72];
    __shared__ float sT[64 * 66];

    const int m0  = blockIdx.x * 64;
    const int y   = blockIdx.y;          // 0..35
    const int mat = y / NH, h = y % NH;
    const int t = threadIdx.x, lane = t & 63, w = t >> 6;
    const int quad = lane >> 4, l15 = lane & 15;
    const int wm = w >> 1, wn = w & 1;

    const float* bias = (mat == 0) ? bq : (mat == 1) ? bk : bv;

    f32x4 acc[2][2];
    #pragma unroll
    for (int r = 0; r < 2; ++r)
        #pragma unroll
        for (int c = 0; c < 2; ++c) acc[r][c] = (f32x4){0.f, 0.f, 0.f, 0.f};

    const int srow = t >> 2, scol = (t & 3) * 16;
    const float* Ag = hs + (size_t)(m0 + srow) * ND + scol;
    const f16* Bg = wt + ((size_t)y * 64 + srow) * ND + scol;

    for (int k0 = 0; k0 < ND; k0 += 64) {
        soft_barrier();
        {
            float4 a0 = *(const float4*)&Ag[k0];
            float4 a1 = *(const float4*)&Ag[k0 + 4];
            float4 a2 = *(const float4*)&Ag[k0 + 8];
            float4 a3 = *(const float4*)&Ag[k0 + 12];
            f16x8 ha, hb;
            ha[0] = (f16)a0.x; ha[1] = (f16)a0.y; ha[2] = (f16)a0.z; ha[3] = (f16)a0.w;
            ha[4] = (f16)a1.x; ha[5] = (f16)a1.y; ha[6] = (f16)a1.z; ha[7] = (f16)a1.w;
            hb[0] = (f16)a2.x; hb[1] = (f16)a2.y; hb[2] = (f16)a2.z; hb[3] = (f16)a2.w;
            hb[4] = (f16)a3.x; hb[5] = (f16)a3.y; hb[6] = (f16)a3.z; hb[7] = (f16)a3.w;
            *(f16x8*)&sA[srow * 72 + scol]     = ha;
            *(f16x8*)&sA[srow * 72 + scol + 8] = hb;
        }
        *(f16x8*)&sB[srow * 72 + scol]     = *(const f16x8*)&Bg[k0];
        *(f16x8*)&sB[srow * 72 + scol + 8] = *(const f16x8*)&Bg[k0 + 8];
        soft_barrier();
        #pragma unroll
        for (int kk = 0; kk < 64; kk += 32) {
            const int ko = kk + quad * 8;
            f16x8 a0 = *(f16x8*)&sA[(32 * wm + l15) * 72 + ko];
            f16x8 a1 = *(f16x8*)&sA[(32 * wm + 16 + l15) * 72 + ko];
            f16x8 b0 = *(f16x8*)&sB[(32 * wn + l15) * 72 + ko];
            f16x8 b1 = *(f16x8*)&sB[(32 * wn + 16 + l15) * 72 + ko];
            acc[0][0] = MFMA16(a0, b0, acc[0][0]);
            acc[0][1] = MFMA16(a0, b1, acc[0][1]);
            acc[1][0] = MFMA16(a1, b0, acc[1][0]);
            acc[1][1] = MFMA16(a1, b1, acc[1][1]);
        }
    }
    soft_barrier();

    const int bb = m0 >> 10;
    const int lbase = m0 & 1023;
    const int bh = bb * NH + h;

    if (mat < 2) {
        #pragma unroll
        for (int r = 0; r < 2; ++r)
            #pragma unroll
            for (int c = 0; c < 2; ++c) {
                const int col = 32 * wn + 16 * c + l15;
                const float bz = bias[h * 64 + col];
                #pragma unroll
                for (int rr = 0; rr < 4; ++rr)
                    sT[(32 * wm + 16 * r + 4 * quad + rr) * 66 + col] = acc[r][c][rr] + bz;
            }
        soft_barrier();
        const int orow = t >> 2, ocb = (t & 3) * 16;
        f16 tmp[16];
        #pragma unroll
        for (int j = 0; j < 8; ++j) {
            float2 x = *(float2*)&sT[orow * 66 + ocb + 2 * j];
            tmp[2 * j] = (f16)x.x; tmp[2 * j + 1] = (f16)x.y;
        }
        f16* dst = ((mat == 0) ? qf : kf) + ((size_t)bh * NL + lbase + orow) * DH + ocb;
        *(f16x8*)dst       = *(f16x8*)&tmp[0];
        *(f16x8*)(dst + 8) = *(f16x8*)&tmp[8];
    } else {
        #pragma unroll
        for (int r = 0; r < 2; ++r)
            #pragma unroll
            for (int c = 0; c < 2; ++c) {
                const int col = 32 * wn + 16 * c + l15;
                const float bz = bias[h * 64 + col];
                #pragma unroll
                for (int rr = 0; rr < 4; ++rr)
                    sT[col * 66 + 32 * wm + 16 * r + 4 * quad + rr] = acc[r][c][rr] + bz;
            }
        soft_barrier();
        const int d = t >> 2, lcb = (t & 3) * 16;
        f16 tmp[16];
        #pragma unroll
        for (int j = 0; j < 8; ++j) {
            float2 x = *(float2*)&sT[d * 66 + lcb + 2 * j];
            tmp[2 * j] = (f16)x.x; tmp[2 * j + 1] = (f16)x.y;
        }
        f16* dst = vt + ((size_t)bh * DH + d) * NL + lbase + lcb;
        *(f16x8*)dst       = *(f16x8*)&tmp[0];
        *(f16x8*)(dst + 8) = *(f16x8*)&tmp[8];
    }
}

// ---------------------------------------------------------------------------
// Kernel C: f16-MFMA flash attention, fused positional band-GEMMs, fused qw.
// Round-11 reschedule (T14 issue-early/write-late, 3 barriers/kt, no drain):
//   B: band GEMMs (reads sK,sE; writes sQEl/sKEl)           | bar_a
//   C: ISSUE K/V/E loads(kt+1)->regs; score MFMA; epilogue  | bar_b
//   D: softmax; ds_write K/V/E(kt+1); ISSUE pf loads(kt+1)  | bar_c
//   E: PV MFMA only (no barrier after; loops to B)
// Hazards: sK overwrite in D (last read C, bar_b); sE overwrite in D (last
// read B, bar_a); sVt other buffer; sQEl/sKEl rewrite in B (last read C(kt-1)
// epilogue, bar_b(kt-1)); pf issue in D (old values last read C epilogue).
// Staging regs kreg/vreg/ereg live C->D: ~160 VGPR, under (256,2) budget.
// ---------------------------------------------------------------------------
__global__ __launch_bounds__(256, 2) void attn_kernel(
    const f16* __restrict__ qf, const f16* __restrict__ kf,
    const f16* __restrict__ vt, const f16* __restrict__ swt,
    const float* __restrict__ mask, const float* __restrict__ struct_m,
    const f16* __restrict__ de16, const float* __restrict__ abs_bias,
    float* __restrict__ out)
{
    __shared__ f16 sK[64 * 72];
    __shared__ f16 sVt[2][64 * 72];
    __shared__ f16 sE[96 * 72];      // E band rows 0..94 (t' = i-j+63); qw scratch in prologue
    __shared__ f16 sQEl[96 * 34];    // [tp][i]
    __shared__ f16 sKEl[96 * 34];    // [tp][j]
    __shared__ float sS[32 * 68];
    __shared__ f16 sP[32 * 72];
    __shared__ float sAlpha[32], sL[32];

    const int l0 = blockIdx.x * 32;
    const int bh = blockIdx.y;
    const int bb = bh / NH, h = bh % NH;
    const int t  = threadIdx.x;
    const int lane  = t & 63;
    const int w     = t >> 6;       // 0..3
    const int quad  = lane >> 4;
    const int l15   = lane & 15;
    const int msub  = w >> 1;       // 0..1
    const int npair = w & 1;        // 0..1

    f16x8 aQ[2], aW[5][2];
    {
        const size_t qrow = ((size_t)bh * NL + l0 + 16 * msub + l15) * DH;
        #pragma unroll
        for (int K = 0; K < 2; ++K)
            aQ[K] = *(const f16x8*)&qf[qrow + 32 * K + 8 * quad];
    }

    // ---- Fused qw: aW[p] fragments of Q_tile @ ssan_w[p,h] ----
    {
        #pragma unroll
        for (int b = 0; b < 2; ++b) {
            const int pb0  = (b == 0) ? 0 : 3;
            const int pcnt = (b == 0) ? 3 : 2;
            #pragma unroll
            for (int pi = 0; pi < 3; ++pi) {
                if (pi < pcnt) {
                    const int p = pb0 + pi;
                    const f16* Wp = swt + ((size_t)(p * NH + h)) * 64 * 64;
                    #pragma unroll
                    for (int ntl = 0; ntl < 2; ++ntl) {
                        const int nt = 2 * npair + ntl;
                        f32x4 c = (f32x4){0.f, 0.f, 0.f, 0.f};
                        #pragma unroll
                        for (int K = 0; K < 2; ++K) {
                            f16x8 bw = *(const f16x8*)&Wp[(size_t)(16 * nt + l15) * 64 + 32 * K + 8 * quad];
                            c = MFMA16(aQ[K], bw, c);
                        }
                        #pragma unroll
                        for (int r = 0; r < 4; ++r)
                            sE[(pi * 32 + 16 * msub + 4 * quad + r) * 72 + 16 * nt + l15] = (f16)c[r];
                    }
                }
            }
            soft_barrier();
            #pragma unroll
            for (int pi = 0; pi < 3; ++pi) {
                if (pi < pcnt) {
                    #pragma unroll
                    for (int K = 0; K < 2; ++K)
                        aW[pb0 + pi][K] =
                            *(const f16x8*)&sE[(pi * 32 + 16 * msub + l15) * 72 + 32 * K + 8 * quad];
                }
            }
            soft_barrier();
        }
    }

    float ab[5];
    #pragma unroll
    for (int p = 0; p < 5; ++p) ab[p] = abs_bias[p * NH + h];

    float pf_st[5][2][4], pf_mask[2];
    f16x8 kreg[2], vreg[2], ereg[3];     // issue-early staging registers

    auto issue_kv = [&](int r0s) {
        const int row = t >> 3, col = (t & 7) * 8;
        const f16* ks = kf + ((size_t)bh * NL + r0s) * DH;
        kreg[0] = *(const f16x8*)&ks[row * 64 + col];
        kreg[1] = *(const f16x8*)&ks[(row + 32) * 64 + col];
        const f16* vs = vt + (size_t)bh * DH * NL + r0s;
        vreg[0] = *(const f16x8*)&vs[(size_t)row * NL + col];
        vreg[1] = *(const f16x8*)&vs[(size_t)(row + 32) * NL + col];
    };
    auto write_kv = [&](int buf) {
        const int row = t >> 3, col = (t & 7) * 8;
        *(f16x8*)&sK[row * 72 + col]             = kreg[0];
        *(f16x8*)&sK[(row + 32) * 72 + col]      = kreg[1];
        *(f16x8*)&sVt[buf][row * 72 + col]       = vreg[0];
        *(f16x8*)&sVt[buf][(row + 32) * 72 + col] = vreg[1];
    };
    auto issue_E = [&](int r0s) {
        const int ebase = l0 - r0s + 960;
        #pragma unroll
        for (int p2 = 0; p2 < 3; ++p2) {
            const int idx = t + 256 * p2;
            const int er = idx >> 3, colE = (idx & 7) * 8;
            if (er < 95)
                ereg[p2] = *(const f16x8*)&de16[(size_t)(ebase + er) * DH + colE];
        }
    };
    auto write_E = [&]() {
        #pragma unroll
        for (int p2 = 0; p2 < 3; ++p2) {
            const int idx = t + 256 * p2;
            const int er = idx >> 3, colE = (idx & 7) * 8;
            if (er < 95)
                *(f16x8*)&sE[er * 72 + colE] = ereg[p2];
        }
    };
    auto prefetch = [&](int r0s) {
        #pragma unroll
        for (int n = 0; n < 2; ++n) {
            const int j = 32 * npair + 16 * n + l15;
            pf_mask[n] = mask[bb * NL + r0s + j];
            #pragma unroll
            for (int r = 0; r < 4; ++r) {
                const int i = 16 * msub + 4 * quad + r;
                #pragma unroll
                for (int p = 0; p < 5; ++p)
                    pf_st[p][n][r] =
                        struct_m[((size_t)(p * NB + bb) * NL + l0 + i) * NL + r0s + j];
            }
        }
    };

    // prologue: stage kt=0 directly
    issue_kv(0);
    issue_E(0);
    write_kv(0);
    write_E();
    prefetch(0);

    const int sm_i = t >> 3;
    const int sm_jb = t & 7;
    float m_cur = -INFINITY, l_cur = 0.f;
    f32x4 O[2];
    O[0] = (f32x4){0.f, 0.f, 0.f, 0.f};
    O[1] = (f32x4){0.f, 0.f, 0.f, 0.f};

    soft_barrier();                        // kt=0 staging visible

    for (int kt = 0; kt < 16; ++kt) {
        const int cur = kt & 1;

        // ---- Phase B: positional band GEMMs (slim per-wave assignment) ----
        {
            // KE: jt = w, nt = 3-w+c (c = 0..2)
            const int krow = (16 * w + l15) * 72;
            f16x8 ak0 = *(f16x8*)&sK[krow + quad * 8];
            f16x8 ak1 = *(f16x8*)&sK[krow + 32 + quad * 8];
            #pragma unroll
            for (int c = 0; c < 3; ++c) {
                const int nt = 3 - w + c;
                const int erow = (16 * nt + l15) * 72;
                f16x8 e0 = *(f16x8*)&sE[erow + quad * 8];
                f16x8 e1 = *(f16x8*)&sE[erow + 32 + quad * 8];
                f32x4 ck = (f32x4){0.f, 0.f, 0.f, 0.f};
                ck = MFMA16(ak0, e0, ck);
                ck = MFMA16(ak1, e1, ck);
                const int base = (16 * nt + l15) * 34 + 16 * w + 4 * quad;
                f16x2 lo = {(f16)ck[0], (f16)ck[1]};
                f16x2 hi = {(f16)ck[2], (f16)ck[3]};
                *(f16x2*)&sKEl[base]     = lo;
                *(f16x2*)&sKEl[base + 2] = hi;
            }
            // QE: mi = msub, nt = qs..qs+qc-1  (A-frag = resident aQ)
            const int qs = 3 * npair + msub;
            const int qc = 3 - npair;
            #pragma unroll
            for (int c = 0; c < 3; ++c) {
                if (c < qc) {
                    const int nt = qs + c;
                    const int erow = (16 * nt + l15) * 72;
                    f16x8 e0 = *(f16x8*)&sE[erow + quad * 8];
                    f16x8 e1 = *(f16x8*)&sE[erow + 32 + quad * 8];
                    f32x4 cq = (f32x4){0.f, 0.f, 0.f, 0.f};
                    cq = MFMA16(aQ[0], e0, cq);
                    cq = MFMA16(aQ[1], e1, cq);
                    const int base = (16 * nt + l15) * 34 + 16 * msub + 4 * quad;
                    f16x2 lo = {(f16)cq[0], (f16)cq[1]};
                    f16x2 hi = {(f16)cq[2], (f16)cq[3]};
                    *(f16x2*)&sQEl[base]     = lo;
                    *(f16x2*)&sQEl[base + 2] = hi;
                }
            }
        }
        soft_barrier();                    // bar_a: sQEl/sKEl published

        // ---- Phase C: issue next-kt K/V/E loads, then score MFMAs ----
        {
            if (kt < 15) {
                issue_kv((kt + 1) * 64);
                issue_E((kt + 1) * 64);
            }

            f32x4 acc[2][6];
            #pragma unroll
            for (int n = 0; n < 2; ++n)
                #pragma unroll
                for (int p = 0; p < 6; ++p)
                    acc[n][p] = (f32x4){0.f, 0.f, 0.f, 0.f};

            #pragma unroll
            for (int K = 0; K < 2; ++K) {
                const int koff = K * 32 + quad * 8;
                f16x8 bk2[2];
                #pragma unroll
                for (int n = 0; n < 2; ++n)
                    bk2[n] = *(f16x8*)&sK[(32 * npair + 16 * n + l15) * 72 + koff];
                #pragma unroll
                for (int n = 0; n < 2; ++n)
                    acc[n][0] = MFMA16(aQ[K], bk2[n], acc[n][0]);
                #pragma unroll
                for (int p = 0; p < 5; ++p)
                    #pragma unroll
                    for (int n = 0; n < 2; ++n)
                        acc[n][1 + p] = MFMA16(aW[p][K], bk2[n], acc[n][1 + p]);
            }

            #pragma unroll
            for (int n = 0; n < 2; ++n) {
                const int j = 32 * npair + 16 * n + l15;
                #pragma unroll
                for (int r = 0; r < 4; ++r) {
                    const int i = 16 * msub + 4 * quad + r;
                    const int tp = i - j + 63;
                    float posv = (float)sQEl[tp * 34 + i] + (float)sKEl[tp * 34 + j];
                    float s = (acc[n][0][r] + posv) * 0.125f + pf_mask[n];
                    #pragma unroll
                    for (int p = 0; p < 5; ++p)
                        s += (acc[n][1 + p][r] + ab[p]) * pf_st[p][n][r];
                    sS[i * 68 + j] = s;
                }
            }
        }
        soft_barrier();                    // bar_b: sS published

        // ---- Phase D: softmax; write staged K/V/E; issue pf loads ----
        {
            float sv[8];
            float smax = -INFINITY;
            #pragma unroll
            for (int k = 0; k < 8; ++k) {
                sv[k] = sS[sm_i * 68 + sm_jb + 8 * k];
                smax = fmaxf(smax, sv[k]);
            }
            #pragma unroll
            for (int off = 4; off > 0; off >>= 1)
                smax = fmaxf(smax, __shfl_xor(smax, off, 8));
            const float m_new = fmaxf(m_cur, smax);
            const float alpha = __expf(m_cur - m_new);
            float rsum = 0.f;
            #pragma unroll
            for (int k = 0; k < 8; ++k) {
                float p = __expf(sv[k] - m_new);
                sP[sm_i * 72 + sm_jb + 8 * k] = (f16)p;
                rsum += p;
            }
            #pragma unroll
            for (int off = 4; off > 0; off >>= 1)
                rsum += __shfl_xor(rsum, off, 8);
            l_cur = l_cur * alpha + rsum;
            m_cur = m_new;
            if (sm_jb == 0) { sAlpha[sm_i] = alpha; sL[sm_i] = l_cur; }

            if (kt < 15) {
                write_kv(cur ^ 1);         // vmcnt covered by C compute + softmax
                write_E();
                prefetch((kt + 1) * 64);   // reg-dest loads for next C epilogue
            }
        }
        soft_barrier();                    // bar_c: sP/alpha + staging published

        // ---- Phase E: PV MFMA only ----
        {
            float a4[4];
            #pragma unroll
            for (int r = 0; r < 4; ++r) a4[r] = sAlpha[16 * msub + 4 * quad + r];
            #pragma unroll
            for (int n = 0; n < 2; ++n)
                #pragma unroll
                for (int r = 0; r < 4; ++r) O[n][r] *= a4[r];

            const int prow = (16 * msub + l15) * 72;
            #pragma unroll
            for (int K = 0; K < 2; ++K) {
                const int koff = K * 32 + quad * 8;
                f16x8 pfr = *(f16x8*)&sP[prow + koff];
                #pragma unroll
                for (int n = 0; n < 2; ++n) {
                    f16x8 vfr = *(f16x8*)&sVt[cur][(32 * npair + 16 * n + l15) * 72 + koff];
                    O[n] = MFMA16(pfr, vfr, O[n]);
                }
            }
        }
    }

    float linv[4];
    #pragma unroll
    for (int r = 0; r < 4; ++r) linv[r] = 1.0f / sL[16 * msub + 4 * quad + r];
    #pragma unroll
    for (int n = 0; n < 2; ++n) {
        const int dh = 32 * npair + 16 * n + l15;
        #pragma unroll
        for (int r = 0; r < 4; ++r) {
            const int i = 16 * msub + 4 * quad + r;
            out[((size_t)bb * NL + l0 + i) * ND + h * DH + dh] = O[n][r] * linv[r];
        }
    }
}

// ---------------------------------------------------------------------------
extern "C" void kernel_launch(void* const* d_in, const int* in_sizes, int n_in,
                              void* d_out, int out_size, void* d_ws, size_t ws_size,
                              hipStream_t stream) {
    const float* hs   = (const float*)d_in[0];
    const float* mask = (const float*)d_in[1];
    const float* stm  = (const float*)d_in[2];
    const float* Wq   = (const float*)d_in[3];
    const float* bq   = (const float*)d_in[4];
    const float* Wk   = (const float*)d_in[5];
    const float* bk   = (const float*)d_in[6];
    const float* Wv   = (const float*)d_in[7];
    const float* bv   = (const float*)d_in[8];
    const float* de   = (const float*)d_in[9];
    const float* sw   = (const float*)d_in[10];
    const float* abb  = (const float*)d_in[11];
    float* outp = (float*)d_out;

    const size_t NQKV = (size_t)NB * NH * NL * DH;       // 1,572,864
    char* ws = (char*)d_ws;
    f16* qf   = (f16*)ws;                 ws += NQKV * 2;
    f16* kf   = (f16*)ws;                 ws += NQKV * 2;
    f16* vtb  = (f16*)ws;                 ws += NQKV * 2;
    f16* wt   = (f16*)ws;                 ws += (size_t)2304 * 768 * 2;
    f16* swt  = (f16*)ws;                 ws += (size_t)245760 * 2;
    f16* de16 = (f16*)ws;                 // 2047*64 f16 = 262 KB

    prep_kernel<<<556, 256, 0, stream>>>(Wq, Wk, Wv, sw, de, wt, swt, de16);
    qkv_kernel<<<dim3(32, 36), 256, 0, stream>>>(hs, wt, bq, bk, bv, qf, kf, vtb);
    attn_kernel<<<dim3(32, 24), 256, 0, stream>>>(qf, kf, vtb, swt,
                                                  mask, stm, de16, abb, outp);
}

// Round 5
// 218.291 us; speedup vs baseline: 2.5794x; 1.0078x over previous
//
#include <hip/hip_runtime.h>
#include <math.h>

#define NB 2
#define NL 1024
#define ND 768
#define NH 12
#define DH 64

typedef _Float16 f16;
typedef _Float16 f16x2 __attribute__((ext_vector_type(2)));
typedef _Float16 f16x4 __attribute__((ext_vector_type(4)));
typedef _Float16 f16x8 __attribute__((ext_vector_type(8)));
typedef float f32x4 __attribute__((ext_vector_type(4)));

#define MFMA16(a, b, c) __builtin_amdgcn_mfma_f32_16x16x32_f16((a), (b), (c), 0, 0, 0)

// LDS-only barrier (does not force vmcnt drain).
__device__ __forceinline__ void soft_barrier() {
    asm volatile("s_waitcnt lgkmcnt(0)\n\ts_barrier" ::: "memory");
}

// ---------------------------------------------------------------------------
// Kernel 0: prep.
//   tiles 0..767    : hs fp32 -> hsf f16
//   tiles 768..1199 : W{q,k,v} -> wt f16 [(mat*12+h)*64+n][k]   (transposed)
//   tiles 1200..1259: ssan_w -> swt f16 [p][h][e][d]            (transposed)
//   tiles 1260..1323: dist_emb fp32 -> de16 f16
// ---------------------------------------------------------------------------
__global__ __launch_bounds__(256) void prep_kernel(
    const float* __restrict__ hs,
    const float* __restrict__ Wq, const float* __restrict__ Wk,
    const float* __restrict__ Wv, const float* __restrict__ sw,
    const float* __restrict__ de,
    f16* __restrict__ hsf, f16* __restrict__ wt, f16* __restrict__ swt,
    f16* __restrict__ de16)
{
    __shared__ float sT[64 * 66];
    const int t = threadIdx.x;
    const int tile = blockIdx.x;

    if (tile < 768) {
        const int base = tile * 2048 + t * 8;
        float4 a = *(const float4*)&hs[base];
        float4 b = *(const float4*)&hs[base + 4];
        f16x8 hv;
        hv[0] = (f16)a.x; hv[1] = (f16)a.y; hv[2] = (f16)a.z; hv[3] = (f16)a.w;
        hv[4] = (f16)b.x; hv[5] = (f16)b.y; hv[6] = (f16)b.z; hv[7] = (f16)b.w;
        *(f16x8*)&hsf[base] = hv;
        return;
    }
    if (tile >= 1260) {
        const int base = (tile - 1260) * 2048 + t * 8;
        if (base < 2047 * 64) {
            float4 a = *(const float4*)&de[base];
            float4 b = *(const float4*)&de[base + 4];
            f16x8 hv;
            hv[0] = (f16)a.x; hv[1] = (f16)a.y; hv[2] = (f16)a.z; hv[3] = (f16)a.w;
            hv[4] = (f16)b.x; hv[5] = (f16)b.y; hv[6] = (f16)b.z; hv[7] = (f16)b.w;
            *(f16x8*)&de16[base] = hv;
        }
        return;
    }

    const float* S; f16* D; int sRS, dRS;
    const int ti = tile - 768;
    if (ti < 432) {
        const int mat = ti / 144, r2 = ti % 144, ht = r2 / 12, kt = r2 % 12;
        const float* W = (mat == 0) ? Wq : (mat == 1) ? Wk : Wv;
        S = W + (size_t)(kt * 64) * ND + ht * 64;
        D = wt + (size_t)((mat * NH + ht) * 64) * ND + kt * 64;
        sRS = ND; dRS = ND;
    } else {
        const int i = ti - 432;
        S = sw + (size_t)i * 4096;
        D = swt + (size_t)i * 4096;
        sRS = 64; dRS = 64;
    }

    {
        const int kk = t >> 2, nb = (t & 3) * 16;
        float v[16];
        #pragma unroll
        for (int j = 0; j < 4; ++j)
            *(float4*)&v[4 * j] = *(const float4*)&S[(size_t)kk * sRS + nb + 4 * j];
        #pragma unroll
        for (int jj = 0; jj < 16; ++jj)
            sT[(nb + jj) * 66 + kk] = v[jj];
    }
    soft_barrier();
    {
        const int n = t >> 2, kb = (t & 3) * 16;
        f16 tmp[16];
        #pragma unroll
        for (int j = 0; j < 8; ++j) {
            float2 x = *(float2*)&sT[n * 66 + kb + 2 * j];
            tmp[2 * j]     = (f16)x.x;
            tmp[2 * j + 1] = (f16)x.y;
        }
        *(f16x8*)&D[(size_t)n * dRS + kb]     = *(f16x8*)&tmp[0];
        *(f16x8*)&D[(size_t)n * dRS + kb + 8] = *(f16x8*)&tmp[8];
    }
}

// ---------------------------------------------------------------------------
// Kernel A v2 (round-12): QKV as ONE GEMM  [2048 x 768] @ Wt[2304 x 768]^T.
// 128x128 tile, BK=64, 4 waves, 64x64 out/wave (acc 4x4), double-buffered
// LDS with ONE barrier per K-iter:
//   barrier -> issue next-tile global loads (regs) -> 32 MFMA/wave over cur
//   buffer -> ds_write regs to OTHER buffer (vmcnt hidden under MFMA).
// Correctness of 1-barrier scheme: a wave arrives at barrier(t) only after
// its MFMA reads of iter t-1 completed (program order), so writes to buf^1
// after barrier(t) cannot race; soft_barrier's lgkmcnt(0) publishes writes.
// x72 f16 pitch => fragment ds_read_b128 is 2-way bank-aliased (free).
// Epilogue: acc -> sC in LDS (reuses staging buffers; V tile stored
// TRANSPOSED so all global writes are 128 B contiguous).
// Grid 16 x 18 (288 blocks); mat = n0/768 uniform per block (768%128==0).
// ---------------------------------------------------------------------------
__global__ __launch_bounds__(256, 2) void qkv_kernel(
    const f16* __restrict__ hsf, const f16* __restrict__ wt,
    const float* __restrict__ bq, const float* __restrict__ bk,
    const float* __restrict__ bv,
    f16* __restrict__ qf, f16* __restrict__ kf, f16* __restrict__ vt)
{
    __shared__ f16 sAB[2][2][128 * 72];    // 73,728 B; reused as sC in epilogue

    const int m0 = blockIdx.x * 128;
    const int n0 = blockIdx.y * 128;
    const int mat = n0 / 768;
    const int h0  = (n0 % 768) / 64;       // first of the 2 heads in this tile
    const int bb  = m0 >> 10;
    const int l0  = m0 & 1023;

    const int t = threadIdx.x, lane = t & 63, w = t >> 6;
    const int quad = lane >> 4, l15 = lane & 15;
    const int wm = w >> 1, wn = w & 1;

    const float* bias = (mat == 0) ? bq : (mat == 1) ? bk : bv;

    // staging: thread t covers row t>>1 (0..127), 32-f16 half (t&1)
    const int srow = t >> 1;
    const int scol = (t & 1) * 32;
    const f16* Ag = hsf + (size_t)(m0 + srow) * ND + scol;
    const f16* Bg = wt  + (size_t)(n0 + srow) * ND + scol;

    f16x8 ar[4], br[4];
    f32x4 acc[4][4];
    #pragma unroll
    for (int mi = 0; mi < 4; ++mi)
        #pragma unroll
        for (int ni = 0; ni < 4; ++ni)
            acc[mi][ni] = (f32x4){0.f, 0.f, 0.f, 0.f};

    // prologue: stage K-tile 0
    #pragma unroll
    for (int j = 0; j < 4; ++j) {
        ar[j] = *(const f16x8*)&Ag[8 * j];
        br[j] = *(const f16x8*)&Bg[8 * j];
    }
    #pragma unroll
    for (int j = 0; j < 4; ++j) {
        *(f16x8*)&sAB[0][0][srow * 72 + scol + 8 * j] = ar[j];
        *(f16x8*)&sAB[0][1][srow * 72 + scol + 8 * j] = br[j];
    }

    for (int kt2 = 0; kt2 < 12; ++kt2) {
        const int cur = kt2 & 1;
        soft_barrier();                    // buf(cur) published
        if (kt2 < 11) {
            const int k0 = (kt2 + 1) * 64;
            #pragma unroll
            for (int j = 0; j < 4; ++j) {
                ar[j] = *(const f16x8*)&Ag[k0 + 8 * j];
                br[j] = *(const f16x8*)&Bg[k0 + 8 * j];
            }
        }
        #pragma unroll
        for (int kk = 0; kk < 64; kk += 32) {
            const int ko = kk + quad * 8;
            f16x8 af[4], bf[4];
            #pragma unroll
            for (int i = 0; i < 4; ++i) {
                af[i] = *(f16x8*)&sAB[cur][0][(64 * wm + 16 * i + l15) * 72 + ko];
                bf[i] = *(f16x8*)&sAB[cur][1][(64 * wn + 16 * i + l15) * 72 + ko];
            }
            #pragma unroll
            for (int mi = 0; mi < 4; ++mi)
                #pragma unroll
                for (int ni = 0; ni < 4; ++ni)
                    acc[mi][ni] = MFMA16(af[mi], bf[ni], acc[mi][ni]);
        }
        if (kt2 < 11) {
            #pragma unroll
            for (int j = 0; j < 4; ++j) {
                *(f16x8*)&sAB[cur ^ 1][0][srow * 72 + scol + 8 * j] = ar[j];
                *(f16x8*)&sAB[cur ^ 1][1][srow * 72 + scol + 8 * j] = br[j];
            }
        }
    }
    soft_barrier();                        // all MFMA reads done; reuse LDS

    // ---- epilogue via LDS tile sC[128][136] (V stored transposed) ----
    f16* sC = (f16*)sAB;
    float bz[4];
    #pragma unroll
    for (int ni = 0; ni < 4; ++ni)
        bz[ni] = bias[(n0 % 768) + 64 * wn + 16 * ni + l15];

    #pragma unroll
    for (int mi = 0; mi < 4; ++mi)
        #pragma unroll
        for (int ni = 0; ni < 4; ++ni) {
            const int col = 64 * wn + 16 * ni + l15;
            #pragma unroll
            for (int r = 0; r < 4; ++r) {
                const int row = 64 * wm + 16 * mi + 4 * quad + r;
                const f16 v = (f16)(acc[mi][ni][r] + bz[ni]);
                if (mat == 2) sC[col * 136 + row] = v;     // transposed
                else          sC[row * 136 + col] = v;
            }
        }
    soft_barrier();

    if (mat < 2) {
        const int row = t >> 1, half = t & 1;             // head = h0+half
        f16* dst = ((mat == 0) ? qf : kf)
                 + ((size_t)(bb * NH + h0 + half) * NL + l0 + row) * DH;
        #pragma unroll
        for (int j = 0; j < 8; ++j)
            *(f16x8*)&dst[8 * j] = *(f16x8*)&sC[row * 136 + 64 * half + 8 * j];
    } else {
        const int c = t >> 1, half = t & 1;               // c = col (d index)
        const int d = c & 63, hh = h0 + (c >> 6);
        f16* dst = vt + ((size_t)(bb * NH + hh) * DH + d) * NL + l0 + 64 * half;
        #pragma unroll
        for (int j = 0; j < 8; ++j)
            *(f16x8*)&dst[8 * j] = *(f16x8*)&sC[c * 136 + 64 * half + 8 * j];
    }
}

// ---------------------------------------------------------------------------
// Kernel C: f16-MFMA flash attention, fused positional band-GEMMs, fused qw.
// (unchanged from round-11/round-4: T14 issue-early/write-late, 3 barriers/kt)
// ---------------------------------------------------------------------------
__global__ __launch_bounds__(256, 2) void attn_kernel(
    const f16* __restrict__ qf, const f16* __restrict__ kf,
    const f16* __restrict__ vt, const f16* __restrict__ swt,
    const float* __restrict__ mask, const float* __restrict__ struct_m,
    const f16* __restrict__ de16, const float* __restrict__ abs_bias,
    float* __restrict__ out)
{
    __shared__ f16 sK[64 * 72];
    __shared__ f16 sVt[2][64 * 72];
    __shared__ f16 sE[96 * 72];      // E band rows 0..94 (t' = i-j+63); qw scratch in prologue
    __shared__ f16 sQEl[96 * 34];    // [tp][i]
    __shared__ f16 sKEl[96 * 34];    // [tp][j]
    __shared__ float sS[32 * 68];
    __shared__ f16 sP[32 * 72];
    __shared__ float sAlpha[32], sL[32];

    const int l0 = blockIdx.x * 32;
    const int bh = blockIdx.y;
    const int bb = bh / NH, h = bh % NH;
    const int t  = threadIdx.x;
    const int lane  = t & 63;
    const int w     = t >> 6;       // 0..3
    const int quad  = lane >> 4;
    const int l15   = lane & 15;
    const int msub  = w >> 1;       // 0..1
    const int npair = w & 1;        // 0..1

    f16x8 aQ[2], aW[5][2];
    {
        const size_t qrow = ((size_t)bh * NL + l0 + 16 * msub + l15) * DH;
        #pragma unroll
        for (int K = 0; K < 2; ++K)
            aQ[K] = *(const f16x8*)&qf[qrow + 32 * K + 8 * quad];
    }

    // ---- Fused qw: aW[p] fragments of Q_tile @ ssan_w[p,h] ----
    {
        #pragma unroll
        for (int b = 0; b < 2; ++b) {
            const int pb0  = (b == 0) ? 0 : 3;
            const int pcnt = (b == 0) ? 3 : 2;
            #pragma unroll
            for (int pi = 0; pi < 3; ++pi) {
                if (pi < pcnt) {
                    const int p = pb0 + pi;
                    const f16* Wp = swt + ((size_t)(p * NH + h)) * 64 * 64;
                    #pragma unroll
                    for (int ntl = 0; ntl < 2; ++ntl) {
                        const int nt = 2 * npair + ntl;
                        f32x4 c = (f32x4){0.f, 0.f, 0.f, 0.f};
                        #pragma unroll
                        for (int K = 0; K < 2; ++K) {
                            f16x8 bw = *(const f16x8*)&Wp[(size_t)(16 * nt + l15) * 64 + 32 * K + 8 * quad];
                            c = MFMA16(aQ[K], bw, c);
                        }
                        #pragma unroll
                        for (int r = 0; r < 4; ++r)
                            sE[(pi * 32 + 16 * msub + 4 * quad + r) * 72 + 16 * nt + l15] = (f16)c[r];
                    }
                }
            }
            soft_barrier();
            #pragma unroll
            for (int pi = 0; pi < 3; ++pi) {
                if (pi < pcnt) {
                    #pragma unroll
                    for (int K = 0; K < 2; ++K)
                        aW[pb0 + pi][K] =
                            *(const f16x8*)&sE[(pi * 32 + 16 * msub + l15) * 72 + 32 * K + 8 * quad];
                }
            }
            soft_barrier();
        }
    }

    float ab[5];
    #pragma unroll
    for (int p = 0; p < 5; ++p) ab[p] = abs_bias[p * NH + h];

    float pf_st[5][2][4], pf_mask[2];
    f16x8 kreg[2], vreg[2], ereg[3];     // issue-early staging registers

    auto issue_kv = [&](int r0s) {
        const int row = t >> 3, col = (t & 7) * 8;
        const f16* ks = kf + ((size_t)bh * NL + r0s) * DH;
        kreg[0] = *(const f16x8*)&ks[row * 64 + col];
        kreg[1] = *(const f16x8*)&ks[(row + 32) * 64 + col];
        const f16* vs = vt + (size_t)bh * DH * NL + r0s;
        vreg[0] = *(const f16x8*)&vs[(size_t)row * NL + col];
        vreg[1] = *(const f16x8*)&vs[(size_t)(row + 32) * NL + col];
    };
    auto write_kv = [&](int buf) {
        const int row = t >> 3, col = (t & 7) * 8;
        *(f16x8*)&sK[row * 72 + col]             = kreg[0];
        *(f16x8*)&sK[(row + 32) * 72 + col]      = kreg[1];
        *(f16x8*)&sVt[buf][row * 72 + col]       = vreg[0];
        *(f16x8*)&sVt[buf][(row + 32) * 72 + col] = vreg[1];
    };
    auto issue_E = [&](int r0s) {
        const int ebase = l0 - r0s + 960;
        #pragma unroll
        for (int p2 = 0; p2 < 3; ++p2) {
            const int idx = t + 256 * p2;
            const int er = idx >> 3, colE = (idx & 7) * 8;
            if (er < 95)
                ereg[p2] = *(const f16x8*)&de16[(size_t)(ebase + er) * DH + colE];
        }
    };
    auto write_E = [&]() {
        #pragma unroll
        for (int p2 = 0; p2 < 3; ++p2) {
            const int idx = t + 256 * p2;
            const int er = idx >> 3, colE = (idx & 7) * 8;
            if (er < 95)
                *(f16x8*)&sE[er * 72 + colE] = ereg[p2];
        }
    };
    auto prefetch = [&](int r0s) {
        #pragma unroll
        for (int n = 0; n < 2; ++n) {
            const int j = 32 * npair + 16 * n + l15;
            pf_mask[n] = mask[bb * NL + r0s + j];
            #pragma unroll
            for (int r = 0; r < 4; ++r) {
                const int i = 16 * msub + 4 * quad + r;
                #pragma unroll
                for (int p = 0; p < 5; ++p)
                    pf_st[p][n][r] =
                        struct_m[((size_t)(p * NB + bb) * NL + l0 + i) * NL + r0s + j];
            }
        }
    };

    // prologue: stage kt=0 directly
    issue_kv(0);
    issue_E(0);
    write_kv(0);
    write_E();
    prefetch(0);

    const int sm_i = t >> 3;
    const int sm_jb = t & 7;
    float m_cur = -INFINITY, l_cur = 0.f;
    f32x4 O[2];
    O[0] = (f32x4){0.f, 0.f, 0.f, 0.f};
    O[1] = (f32x4){0.f, 0.f, 0.f, 0.f};

    soft_barrier();                        // kt=0 staging visible

    for (int kt = 0; kt < 16; ++kt) {
        const int cur = kt & 1;

        // ---- Phase B: positional band GEMMs (slim per-wave assignment) ----
        {
            // KE: jt = w, nt = 3-w+c (c = 0..2)
            const int krow = (16 * w + l15) * 72;
            f16x8 ak0 = *(f16x8*)&sK[krow + quad * 8];
            f16x8 ak1 = *(f16x8*)&sK[krow + 32 + quad * 8];
            #pragma unroll
            for (int c = 0; c < 3; ++c) {
                const int nt = 3 - w + c;
                const int erow = (16 * nt + l15) * 72;
                f16x8 e0 = *(f16x8*)&sE[erow + quad * 8];
                f16x8 e1 = *(f16x8*)&sE[erow + 32 + quad * 8];
                f32x4 ck = (f32x4){0.f, 0.f, 0.f, 0.f};
                ck = MFMA16(ak0, e0, ck);
                ck = MFMA16(ak1, e1, ck);
                const int base = (16 * nt + l15) * 34 + 16 * w + 4 * quad;
                f16x2 lo = {(f16)ck[0], (f16)ck[1]};
                f16x2 hi = {(f16)ck[2], (f16)ck[3]};
                *(f16x2*)&sKEl[base]     = lo;
                *(f16x2*)&sKEl[base + 2] = hi;
            }
            // QE: mi = msub, nt = qs..qs+qc-1  (A-frag = resident aQ)
            const int qs = 3 * npair + msub;
            const int qc = 3 - npair;
            #pragma unroll
            for (int c = 0; c < 3; ++c) {
                if (c < qc) {
                    const int nt = qs + c;
                    const int erow = (16 * nt + l15) * 72;
                    f16x8 e0 = *(f16x8*)&sE[erow + quad * 8];
                    f16x8 e1 = *(f16x8*)&sE[erow + 32 + quad * 8];
                    f32x4 cq = (f32x4){0.f, 0.f, 0.f, 0.f};
                    cq = MFMA16(aQ[0], e0, cq);
                    cq = MFMA16(aQ[1], e1, cq);
                    const int base = (16 * nt + l15) * 34 + 16 * msub + 4 * quad;
                    f16x2 lo = {(f16)cq[0], (f16)cq[1]};
                    f16x2 hi = {(f16)cq[2], (f16)cq[3]};
                    *(f16x2*)&sQEl[base]     = lo;
                    *(f16x2*)&sQEl[base + 2] = hi;
                }
            }
        }
        soft_barrier();                    // bar_a: sQEl/sKEl published

        // ---- Phase C: issue next-kt K/V/E loads, then score MFMAs ----
        {
            if (kt < 15) {
                issue_kv((kt + 1) * 64);
                issue_E((kt + 1) * 64);
            }

            f32x4 acc[2][6];
            #pragma unroll
            for (int n = 0; n < 2; ++n)
                #pragma unroll
                for (int p = 0; p < 6; ++p)
                    acc[n][p] = (f32x4){0.f, 0.f, 0.f, 0.f};

            #pragma unroll
            for (int K = 0; K < 2; ++K) {
                const int koff = K * 32 + quad * 8;
                f16x8 bk2[2];
                #pragma unroll
                for (int n = 0; n < 2; ++n)
                    bk2[n] = *(f16x8*)&sK[(32 * npair + 16 * n + l15) * 72 + koff];
                #pragma unroll
                for (int n = 0; n < 2; ++n)
                    acc[n][0] = MFMA16(aQ[K], bk2[n], acc[n][0]);
                #pragma unroll
                for (int p = 0; p < 5; ++p)
                    #pragma unroll
                    for (int n = 0; n < 2; ++n)
                        acc[n][1 + p] = MFMA16(aW[p][K], bk2[n], acc[n][1 + p]);
            }

            #pragma unroll
            for (int n = 0; n < 2; ++n) {
                const int j = 32 * npair + 16 * n + l15;
                #pragma unroll
                for (int r = 0; r < 4; ++r) {
                    const int i = 16 * msub + 4 * quad + r;
                    const int tp = i - j + 63;
                    float posv = (float)sQEl[tp * 34 + i] + (float)sKEl[tp * 34 + j];
                    float s = (acc[n][0][r] + posv) * 0.125f + pf_mask[n];
                    #pragma unroll
                    for (int p = 0; p < 5; ++p)
                        s += (acc[n][1 + p][r] + ab[p]) * pf_st[p][n][r];
                    sS[i * 68 + j] = s;
                }
            }
        }
        soft_barrier();                    // bar_b: sS published

        // ---- Phase D: softmax; write staged K/V/E; issue pf loads ----
        {
            float sv[8];
            float smax = -INFINITY;
            #pragma unroll
            for (int k = 0; k < 8; ++k) {
                sv[k] = sS[sm_i * 68 + sm_jb + 8 * k];
                smax = fmaxf(smax, sv[k]);
            }
            #pragma unroll
            for (int off = 4; off > 0; off >>= 1)
                smax = fmaxf(smax, __shfl_xor(smax, off, 8));
            const float m_new = fmaxf(m_cur, smax);
            const float alpha = __expf(m_cur - m_new);
            float rsum = 0.f;
            #pragma unroll
            for (int k = 0; k < 8; ++k) {
                float p = __expf(sv[k] - m_new);
                sP[sm_i * 72 + sm_jb + 8 * k] = (f16)p;
                rsum += p;
            }
            #pragma unroll
            for (int off = 4; off > 0; off >>= 1)
                rsum += __shfl_xor(rsum, off, 8);
            l_cur = l_cur * alpha + rsum;
            m_cur = m_new;
            if (sm_jb == 0) { sAlpha[sm_i] = alpha; sL[sm_i] = l_cur; }

            if (kt < 15) {
                write_kv(cur ^ 1);         // vmcnt covered by C compute + softmax
                write_E();
                prefetch((kt + 1) * 64);   // reg-dest loads for next C epilogue
            }
        }
        soft_barrier();                    // bar_c: sP/alpha + staging published

        // ---- Phase E: PV MFMA only ----
        {
            float a4[4];
            #pragma unroll
            for (int r = 0; r < 4; ++r) a4[r] = sAlpha[16 * msub + 4 * quad + r];
            #pragma unroll
            for (int n = 0; n < 2; ++n)
                #pragma unroll
                for (int r = 0; r < 4; ++r) O[n][r] *= a4[r];

            const int prow = (16 * msub + l15) * 72;
            #pragma unroll
            for (int K = 0; K < 2; ++K) {
                const int koff = K * 32 + quad * 8;
                f16x8 pfr = *(f16x8*)&sP[prow + koff];
                #pragma unroll
                for (int n = 0; n < 2; ++n) {
                    f16x8 vfr = *(f16x8*)&sVt[cur][(32 * npair + 16 * n + l15) * 72 + koff];
                    O[n] = MFMA16(pfr, vfr, O[n]);
                }
            }
        }
    }

    float linv[4];
    #pragma unroll
    for (int r = 0; r < 4; ++r) linv[r] = 1.0f / sL[16 * msub + 4 * quad + r];
    #pragma unroll
    for (int n = 0; n < 2; ++n) {
        const int dh = 32 * npair + 16 * n + l15;
        #pragma unroll
        for (int r = 0; r < 4; ++r) {
            const int i = 16 * msub + 4 * quad + r;
            out[((size_t)bb * NL + l0 + i) * ND + h * DH + dh] = O[n][r] * linv[r];
        }
    }
}

// ---------------------------------------------------------------------------
extern "C" void kernel_launch(void* const* d_in, const int* in_sizes, int n_in,
                              void* d_out, int out_size, void* d_ws, size_t ws_size,
                              hipStream_t stream) {
    const float* hs   = (const float*)d_in[0];
    const float* mask = (const float*)d_in[1];
    const float* stm  = (const float*)d_in[2];
    const float* Wq   = (const float*)d_in[3];
    const float* bq   = (const float*)d_in[4];
    const float* Wk   = (const float*)d_in[5];
    const float* bk   = (const float*)d_in[6];
    const float* Wv   = (const float*)d_in[7];
    const float* bv   = (const float*)d_in[8];
    const float* de   = (const float*)d_in[9];
    const float* sw   = (const float*)d_in[10];
    const float* abb  = (const float*)d_in[11];
    float* outp = (float*)d_out;

    const size_t NQKV = (size_t)NB * NH * NL * DH;       // 1,572,864
    char* ws = (char*)d_ws;
    f16* qf   = (f16*)ws;                 ws += NQKV * 2;
    f16* kf   = (f16*)ws;                 ws += NQKV * 2;
    f16* vtb  = (f16*)ws;                 ws += NQKV * 2;
    f16* hsf  = (f16*)ws;                 ws += NQKV * 2;
    f16* wt   = (f16*)ws;                 ws += (size_t)2304 * 768 * 2;
    f16* swt  = (f16*)ws;                 ws += (size_t)245760 * 2;
    f16* de16 = (f16*)ws;                 // 2047*64 f16 = 262 KB

    prep_kernel<<<1324, 256, 0, stream>>>(hs, Wq, Wk, Wv, sw, de,
                                          hsf, wt, swt, de16);
    qkv_kernel<<<dim3(16, 18), 256, 0, stream>>>(hsf, wt, bq, bk, bv, qf, kf, vtb);
    attn_kernel<<<dim3(32, 24), 256, 0, stream>>>(qf, kf, vtb, swt,
                                                  mask, stm, de16, abb, outp);
}